// Round 9
// baseline (376.274 us; speedup 1.0000x reference)
//
#include <hip/hip_runtime.h>
#include <hip/hip_bf16.h>
#include <cmath>

typedef unsigned short u16;
typedef __attribute__((ext_vector_type(8))) short short8;
typedef __attribute__((ext_vector_type(4))) float f32x4;
typedef __attribute__((ext_vector_type(16))) float f32x16;
typedef __attribute__((ext_vector_type(4))) unsigned short u16x4;
typedef __attribute__((ext_vector_type(4))) unsigned int u32x4;

#define AT_B 2
#define AT_T 2048
#define AT_H 16
#define AT_D 128
#define AT_M 2048
#define NROW (AT_B*AT_T)   // 4096
#define HD   (AT_H*AT_D)   // 2048

__device__ __forceinline__ u16 f2bf(float f) {
    union { float f; unsigned u; } v; v.f = f;
    unsigned u = v.u;
    unsigned r = u + 0x7fffu + ((u >> 16) & 1u);
    return (u16)(r >> 16);
}
__device__ __forceinline__ float bf2f(u16 h) {
    union { unsigned u; float f; } v; v.u = ((unsigned)h) << 16;
    return v.f;
}
__device__ __forceinline__ unsigned pack_bf2(float a, float b) {
    __hip_bfloat162 t = __float22bfloat162_rn(make_float2(a, b));
    union { __hip_bfloat162 h; unsigned u; } v; v.h = t;
    return v.u;
}

// async global->LDS DMA, 16B per lane. LDS dest = wave-uniform base + lane*16.
__device__ __forceinline__ void gload16(const u16* g, u16* l) {
    __builtin_amdgcn_global_load_lds(
        (const __attribute__((address_space(1))) void*)g,
        (__attribute__((address_space(3))) void*)l, 16, 0, 0);
}

// ---------------- elementwise cast fp32 -> bf16 (vec4) ----------------
__global__ void cast_bf16_k(const float* __restrict__ in, u16* __restrict__ out, int n4) {
    int i = blockIdx.x * 256 + threadIdx.x;
    if (i >= n4) return;
    float4 v = ((const float4*)in)[i];
    u16x4 o;
    o.x = f2bf(v.x); o.y = f2bf(v.y); o.z = f2bf(v.z); o.w = f2bf(v.w);
    ((u16x4*)out)[i] = o;
}

// ------------- QKV weight transpose-cast: 3 weights in one launch -------------
__global__ void tcast3_k(const float* __restrict__ wq, const float* __restrict__ wk,
                         const float* __restrict__ wv, u16* __restrict__ out) {
    __shared__ float tile[32][33];
    int bx = blockIdx.x, by = blockIdx.y, bz = blockIdx.z;
    int which = bz >> 4, h = bz & 15;
    const float* ip = (which == 0 ? wq : which == 1 ? wk : wv) + (size_t)h * AT_M * AT_D;
    u16* op = out + ((size_t)which * AT_H + h) * AT_M * AT_D;
    int tx = threadIdx.x, ty = threadIdx.y;
    #pragma unroll
    for (int j = 0; j < 32; j += 8)
        tile[ty + j][tx] = ip[(size_t)(by * 32 + ty + j) * AT_D + bx * 32 + tx];
    __syncthreads();
    #pragma unroll
    for (int j = 0; j < 32; j += 8)
        op[(size_t)(bx * 32 + ty + j) * AT_M + by * 32 + tx] = f2bf(tile[tx][ty + j]);
}

// ------------- transpose-cast: in[R][C] fp32 -> out[C][R] bf16 (w_ao) -------------
__global__ void tcast_k(const float* __restrict__ in, u16* __restrict__ out, int R, int C) {
    __shared__ float tile[32][33];
    int bx = blockIdx.x, by = blockIdx.y;
    int tx = threadIdx.x, ty = threadIdx.y;
    #pragma unroll
    for (int j = 0; j < 32; j += 8)
        tile[ty + j][tx] = in[(size_t)(by * 32 + ty + j) * C + bx * 32 + tx];
    __syncthreads();
    #pragma unroll
    for (int j = 0; j < 32; j += 8)
        out[(size_t)(bx * 32 + ty + j) * R + by * 32 + tx] = f2bf(tile[tx][ty + j]);
}

// ------------- batched transpose bf16 -> bf16: in[bz][R][C] -> out[bz][C][R] -------------
__global__ void tbf16_k(const u16* __restrict__ in, u16* __restrict__ out, int R, int C) {
    __shared__ u16 tile[32][33];
    int bx = blockIdx.x, by = blockIdx.y, bz = blockIdx.z;
    const u16* ip = in + (size_t)bz * R * C;
    u16* op = out + (size_t)bz * R * C;
    int tx = threadIdx.x, ty = threadIdx.y;
    #pragma unroll
    for (int j = 0; j < 32; j += 8)
        tile[ty + j][tx] = ip[(size_t)(by * 32 + ty + j) * C + bx * 32 + tx];
    __syncthreads();
    #pragma unroll
    for (int j = 0; j < 32; j += 8)
        op[(size_t)(bx * 32 + ty + j) * R + by * 32 + tx] = tile[tx][ty + j];
}

// ---------------- RoPE in place, short8-vectorized (16B/lane); q scaled by 1/128 ----------------
// thread i handles d = dg*8..dg*8+7 (dg = i&7) of row rest = i>>3 ((b*T+t)*H + h).
__global__ void rope_k(u16* __restrict__ q, u16* __restrict__ k, int total8) {
    int i = blockIdx.x * 256 + threadIdx.x;
    if (i >= total8) return;
    const int dg = i & 7;
    const int rest = i >> 3;               // (b*T+t)*H + h
    const int t = (rest >> 4) & (AT_T - 1);
    const size_t base = (size_t)rest * 128 + dg * 8;
    short8 qe8 = *(const short8*)&q[base], qo8 = *(const short8*)&q[base + 64];
    short8 ke8 = *(const short8*)&k[base], ko8 = *(const short8*)&k[base + 64];
    short8 rqe, rqo, rke, rko;
    const float qs = 0.0078125f;  // 1/128, exact
    #pragma unroll
    for (int j = 0; j < 8; ++j) {
        const int d = dg * 8 + j;
        float freq = __expf(-(float)d * (9.210340371976184f / 64.0f)); // 10000^{-d/64}
        float s, c;
        sincosf((float)t * freq, &s, &c);
        float qe = bf2f((u16)qe8[j]), qo = bf2f((u16)qo8[j]);
        rqe[j] = (short)f2bf((qe * c - qo * s) * qs);
        rqo[j] = (short)f2bf((qe * s + qo * c) * qs);
        float ke = bf2f((u16)ke8[j]), ko = bf2f((u16)ko8[j]);
        rke[j] = (short)f2bf(ke * c - ko * s);
        rko[j] = (short)f2bf(ke * s + ko * c);
    }
    *(short8*)&q[base]      = rqe;
    *(short8*)&q[base + 64] = rqo;
    *(short8*)&k[base]      = rke;
    *(short8*)&k[base + 64] = rko;
}

// =================================================================================
// 256x192-tile QKV GEMM (proven R3 structure, 117.6 us / 876 TF), 512 threads.
// global_load_lds staging, involution chunk swizzle, dbuf LDS, counted vmcnt(7).
// =================================================================================
#define G_ASZ (256*64)
#define G_BSZ (192*64)
#define G_STRIDE (G_ASZ + G_BSZ)
__global__ __launch_bounds__(512, 2) void gemm256_qkv_k(
    const u16* __restrict__ A, const u16* __restrict__ Bt, u16* __restrict__ Cv,
    int M, int N, int K)
{
    __shared__ __align__(1024) u16 smem[2 * G_STRIDE];   // 112 KiB
    const int tid  = threadIdx.x;
    const int wave = tid >> 6, lane = tid & 63;
    const int quad = lane >> 4, l16 = lane & 15;
    const int wr = wave >> 2, wc = wave & 3;
    const int m0 = blockIdx.y * 256, n0 = blockIdx.x * 192;

    const int rl = lane >> 3;               // 0..7
    const int jc = (lane & 7) ^ rl;         // pre-swizzled source k-chunk
    const u16* ga = A  + (size_t)(m0 + wave * 8 + rl) * K + jc * 8;
    const u16* gb = Bt + (size_t)(n0 + wave * 8 + rl) * K + jc * 8;
    const int ldst = (wave * 64) * 8;

    f32x4 zero = {0.f, 0.f, 0.f, 0.f};
    f32x4 acc[8][3];
    #pragma unroll
    for (int i = 0; i < 8; i++)
        #pragma unroll
        for (int j = 0; j < 3; j++) acc[i][j] = zero;

    const int NT = K >> 6;

    {
        #pragma unroll
        for (int i = 0; i < 4; ++i) gload16(ga + (size_t)(i * 64) * K,      smem + i * 512 * 8 + ldst);
        #pragma unroll
        for (int i = 0; i < 3; ++i) gload16(gb + (size_t)(i * 64) * K,      smem + G_ASZ + i * 512 * 8 + ldst);
        #pragma unroll
        for (int i = 0; i < 4; ++i) gload16(ga + (size_t)(i * 64) * K + 64, smem + G_STRIDE + i * 512 * 8 + ldst);
        #pragma unroll
        for (int i = 0; i < 3; ++i) gload16(gb + (size_t)(i * 64) * K + 64, smem + G_STRIDE + G_ASZ + i * 512 * 8 + ldst);
    }
    asm volatile("s_waitcnt vmcnt(7)" ::: "memory");
    __builtin_amdgcn_s_barrier();
    asm volatile("" ::: "memory");

    const int arow = (wr * 128 + l16) * 64;
    const int brow = (wc * 48  + l16) * 64;
    const int rsw  = l16 & 7;

    for (int t = 0; t < NT; ++t) {
        const int boff = (t & 1) * G_STRIDE;
        const u16* as = smem + boff;
        const u16* bs = smem + boff + G_ASZ;
        #pragma unroll
        for (int ks = 0; ks < 2; ++ks) {
            const int ch = ((ks * 4 + quad) ^ rsw) * 8;
            short8 af[8], bfr[3];
            #pragma unroll
            for (int mf = 0; mf < 8; ++mf)
                af[mf] = *(const short8*)&as[arow + mf * (16 * 64) + ch];
            #pragma unroll
            for (int nf = 0; nf < 3; ++nf)
                bfr[nf] = *(const short8*)&bs[brow + nf * (16 * 64) + ch];
            #pragma unroll
            for (int mf = 0; mf < 8; ++mf)
                #pragma unroll
                for (int nf = 0; nf < 3; ++nf)
                    acc[mf][nf] = __builtin_amdgcn_mfma_f32_16x16x32_bf16(af[mf], bfr[nf], acc[mf][nf], 0, 0, 0);
        }
        if (t + 1 < NT) {
            asm volatile("s_waitcnt lgkmcnt(0)" ::: "memory");
            __builtin_amdgcn_s_barrier();
            asm volatile("" ::: "memory");
            if (t + 2 < NT) {
                const int kk = (t + 2) * 64;
                u16* asw = smem + boff;
                u16* bsw = smem + boff + G_ASZ;
                #pragma unroll
                for (int i = 0; i < 4; ++i)
                    gload16(ga + (size_t)(i * 64) * K + kk, asw + i * 512 * 8 + ldst);
                #pragma unroll
                for (int i = 0; i < 3; ++i)
                    gload16(gb + (size_t)(i * 64) * K + kk, bsw + i * 512 * 8 + ldst);
                asm volatile("s_waitcnt vmcnt(7)" ::: "memory");
            } else {
                asm volatile("s_waitcnt vmcnt(0)" ::: "memory");
            }
            __builtin_amdgcn_s_barrier();
            asm volatile("" ::: "memory");
        }
    }

    #pragma unroll
    for (int mf = 0; mf < 8; ++mf)
        #pragma unroll
        for (int nf = 0; nf < 3; ++nf) {
            int col = n0 + wc * 48 + nf * 16 + l16;
            size_t base = ((size_t)(col >> 11) * M) * 2048 + (col & 2047);
            #pragma unroll
            for (int r = 0; r < 4; ++r) {
                int row = m0 + wr * 128 + mf * 16 + quad * 4 + r;
                Cv[base + (size_t)row * 2048] = f2bf(acc[mf][nf][r]);
            }
        }
}

// ---------------- GEMM: C[M][N] = A[M][K] * Bt[N][K]^T  (bf16 in, fp32 acc) ----------------
template<int FP32OUT>
__global__ __launch_bounds__(256, 2) void gemm_bt_k(
    const u16* __restrict__ A, const u16* __restrict__ Bt, void* __restrict__ Cv,
    int M, int N, int K)
{
    __shared__ u16 As[128 * 64];
    __shared__ u16 Bs[128 * 64];
    const int tid = threadIdx.x, wave = tid >> 6, lane = tid & 63;
    const int quad = lane >> 4, l16 = lane & 15;
    const int m0 = blockIdx.y * 128, n0 = blockIdx.x * 128;
    const int mw = (wave & 1) * 64, nw = (wave >> 1) * 64;

    f32x4 zero = {0.f, 0.f, 0.f, 0.f};
    f32x4 acc[4][4];
    #pragma unroll
    for (int i = 0; i < 4; i++)
        #pragma unroll
        for (int j = 0; j < 4; j++) acc[i][j] = zero;

    const int sr = tid >> 3;          // 0..31
    const int sj = tid & 7;           // k-chunk
    const u16* ga0 = A  + (size_t)(m0 + sr) * K + sj * 8;
    const u16* gb0 = Bt + (size_t)(n0 + sr) * K + sj * 8;
    int woff[4];
    #pragma unroll
    for (int it = 0; it < 4; ++it) {
        int r = it * 32 + sr;
        woff[it] = r * 64 + ((sj ^ (r & 7)) * 8);
    }

    short8 abuf[4], bbuf[4];
    #pragma unroll
    for (int it = 0; it < 4; ++it) {
        abuf[it] = *(const short8*)(ga0 + (size_t)(it * 32) * K);
        bbuf[it] = *(const short8*)(gb0 + (size_t)(it * 32) * K);
    }
    #pragma unroll
    for (int it = 0; it < 4; ++it) {
        *(short8*)&As[woff[it]] = abuf[it];
        *(short8*)&Bs[woff[it]] = bbuf[it];
    }
    __syncthreads();

    const int rsw = l16 & 7;

    for (int kk = 0; kk < K; kk += 64) {
        const bool pre = (kk + 64 < K);
        if (pre) {
            #pragma unroll
            for (int it = 0; it < 4; ++it) {
                abuf[it] = *(const short8*)(ga0 + (size_t)(it * 32) * K + (kk + 64));
                bbuf[it] = *(const short8*)(gb0 + (size_t)(it * 32) * K + (kk + 64));
            }
        }
        #pragma unroll
        for (int ks = 0; ks < 2; ks++) {
            const int ch = ((ks * 4 + quad) ^ rsw) * 8;
            short8 af[4], bfr[4];
            #pragma unroll
            for (int mf = 0; mf < 4; mf++)
                af[mf] = *(const short8*)&As[(mw + mf * 16 + l16) * 64 + ch];
            #pragma unroll
            for (int nf = 0; nf < 4; nf++)
                bfr[nf] = *(const short8*)&Bs[(nw + nf * 16 + l16) * 64 + ch];
            #pragma unroll
            for (int mf = 0; mf < 4; mf++)
                #pragma unroll
                for (int nf = 0; nf < 4; nf++)
                    acc[mf][nf] = __builtin_amdgcn_mfma_f32_16x16x32_bf16(af[mf], bfr[nf], acc[mf][nf], 0, 0, 0);
        }
        if (pre) {
            __syncthreads();
            #pragma unroll
            for (int it = 0; it < 4; ++it) {
                *(short8*)&As[woff[it]] = abuf[it];
                *(short8*)&Bs[woff[it]] = bbuf[it];
            }
            __syncthreads();
        }
    }

    #pragma unroll
    for (int mf = 0; mf < 4; mf++)
        #pragma unroll
        for (int nf = 0; nf < 4; nf++)
            #pragma unroll
            for (int r = 0; r < 4; r++) {
                int row = m0 + mw + mf * 16 + quad * 4 + r;
                int col = n0 + nw + nf * 16 + l16;
                if (FP32OUT) ((float*)Cv)[(size_t)row * N + col] = acc[mf][nf][r];
                else         ((u16*) Cv)[(size_t)row * N + col] = f2bf(acc[mf][nf][r]);
            }
}

// =================================================================================
// Flash attention v2: 32x32 MFMA, swapped QK^T (keys in registers), in-register
// softmax + permlane32_swap P-fragment build. 256 threads = 4 waves x 32 q-rows.
// NEW (R9): XCD-locality block mapping — all 16 q-blocks of one (b,h) land on one
// XCD consecutively (bid%8 = XCD slot), so K/V (1 MB per (b,h)) stays L2-resident:
// HBM K/V traffic ~270 MB -> ~35 MB. Per-XCD work exactly equal (4 pairs x 272
// tiles); qb ascending for first half, descending for second half pairs same-sized
// blocks across co-resident CU rounds.
// =================================================================================
__device__ __forceinline__ void stage_kv32(u16* dst, const u16* kgp, const u16* vgp,
                                           int kt, int wave, int lane) {
    #pragma unroll
    for (int i = 0; i < 4; ++i) {
        const int g = i * 4 + wave;
        const int krow = g * 4 + (lane >> 4);
        const int kc = (lane & 15) ^ (krow & 7);
        gload16(kgp + (size_t)(kt * 64 + krow) * 2048 + kc * 8, dst + g * 512);
        const int vrow = g * 8 + (lane >> 3);
        const int vc = (lane & 7) ^ (vrow & 7);
        gload16(vgp + (size_t)vrow * AT_T + kt * 64 + vc * 8, dst + 8192 + g * 512);
    }
}

__global__ __launch_bounds__(256, 2) void attn32_k(
    const u16* __restrict__ q, const u16* __restrict__ k,
    const u16* __restrict__ vt, u16* __restrict__ o)
{
    __shared__ __align__(1024) u16 smem[2 * 16384];   // dbuf x (Ks 16KB + Vs 16KB)
    const int tid = threadIdx.x, wave = tid >> 6, lane = tid & 63;
    const int l32 = lane & 31, hi = lane >> 5;

    // XCD-locality mapping: c = bid&7 (XCD slot), j = bid>>3 (0..63);
    // pair p = c*4 + (j>>4) -> (h,b); qb = j&15, reversed for second half (j>=32).
    const int bid = blockIdx.x;
    const int c = bid & 7, j = bid >> 3;
    const int pp = c * 4 + (j >> 4);
    const int h = pp & 15, b = pp >> 4;
    const int qb = (j >> 5) ? (15 - (j & 15)) : (j & 15);
    const int nkt = 2 * qb + 2;

    const u16* kgp = k  + ((size_t)(b * AT_T) * AT_H + h) * 128;
    const u16* vgp = vt + ((size_t)(b * AT_H + h) * 128) * (size_t)AT_T;

    // Q in regs: qf[kc] = Q[qrow][d = kc*16 + hi*8 + (0..8)]  (B-frag for 32x32x16)
    short8 qf[8];
    {
        const u16* qp = q + ((size_t)(b * AT_T + qb * 128 + wave * 32 + l32) * AT_H + h) * 128 + hi * 8;
        #pragma unroll
        for (int kc = 0; kc < 8; ++kc)
            qf[kc] = *(const short8*)(qp + kc * 16);
    }

    const f32x16 z16 = {0.f,0.f,0.f,0.f,0.f,0.f,0.f,0.f,0.f,0.f,0.f,0.f,0.f,0.f,0.f,0.f};
    f32x16 Oacc[4];
    #pragma unroll
    for (int i = 0; i < 4; ++i) Oacc[i] = z16;
    float l_i = 0.f;

    // prologue: stage tiles 0 and 1, wait tile 0 (vmcnt(8) leaves tile1's 8 in flight)
    stage_kv32(smem,          kgp, vgp, 0, wave, lane);
    stage_kv32(smem + 16384,  kgp, vgp, 1, wave, lane);
    asm volatile("s_waitcnt vmcnt(8)" ::: "memory");
    __builtin_amdgcn_s_barrier();
    asm volatile("" ::: "memory");

    for (int kt = 0; kt < nkt; ++kt) {
        u16* buf = smem + (kt & 1) * 16384;
        const u16* Ks = buf;
        const u16* Vs = buf + 8192;
        const int lkey0 = kt * 64 - qb * 128;      // block-local key base (may be <0)
        const bool act = (lkey0 <= wave * 32 + 31); // wave-uniform skip of fully-masked tiles

        if (act) {
            // ---- QK^T: acc[kch][reg] = S[key][qrow=l32]; keys = (r&3)+8*(r>>2)+4*hi+32*kch
            f32x16 acc[2];
            acc[0] = z16; acc[1] = z16;
            #pragma unroll
            for (int kch = 0; kch < 2; ++kch) {
                #pragma unroll
                for (int kc = 0; kc < 8; ++kc) {
                    const int row = kch * 32 + l32;
                    const int cc = (kc * 2 + hi) ^ (lane & 7);
                    short8 af = *(const short8*)&Ks[row * 128 + cc * 8];
                    acc[kch] = __builtin_amdgcn_mfma_f32_32x32x16_bf16(af, qf[kc], acc[kch], 0, 0, 0);
                }
            }
            // ---- masked exp (max-free) + row-sum
            float rs = 0.f;
            #pragma unroll
            for (int kch = 0; kch < 2; ++kch)
                #pragma unroll
                for (int r = 0; r < 16; ++r) {
                    const int keyb = lkey0 + kch * 32 + (r & 3) + 8 * (r >> 2) + 4 * hi;
                    float sv = acc[kch][r];
                    sv = (keyb > wave * 32 + l32) ? -1e30f : sv;
                    const float e = __expf(sv);
                    acc[kch][r] = e;
                    rs += e;
                }
            rs += __shfl_xor(rs, 32, 64);   // lanes l and l+32 hold the same qrow
            l_i += rs;
            // ---- PV: per 16-key window, build P A-frag via cvt_pk + 2 permlane32_swap
            #pragma unroll
            for (int w16 = 0; w16 < 4; ++w16) {
                const int ch = w16 >> 1, rb = (w16 & 1) * 8;
                unsigned A0 = pack_bf2(acc[ch][rb + 0], acc[ch][rb + 1]);
                unsigned A1 = pack_bf2(acc[ch][rb + 2], acc[ch][rb + 3]);
                unsigned B0 = pack_bf2(acc[ch][rb + 4], acc[ch][rb + 5]);
                unsigned B1 = pack_bf2(acc[ch][rb + 6], acc[ch][rb + 7]);
                asm volatile("v_permlane32_swap_b32 %0, %1" : "+v"(A0), "+v"(B0));
                asm volatile("v_permlane32_swap_b32 %0, %1" : "+v"(A1), "+v"(B1));
                union { u32x4 w; short8 s; } pa;
                pa.w.x = A0; pa.w.y = A1; pa.w.z = B0; pa.w.w = B1;
                #pragma unroll
                for (int dblk = 0; dblk < 4; ++dblk) {
                    const int rowv = dblk * 32 + l32;
                    const int cv = (w16 * 2 + hi) ^ (lane & 7);
                    short8 vf = *(const short8*)&Vs[rowv * 64 + cv * 8];
                    Oacc[dblk] = __builtin_amdgcn_mfma_f32_32x32x16_bf16(pa.s, vf, Oacc[dblk], 0, 0, 0);
                }
            }
        }

        // ---- barrier pair with liveness-correct staging (R3 pattern, vmcnt(8))
        asm volatile("s_waitcnt lgkmcnt(0)" ::: "memory");
        __builtin_amdgcn_s_barrier();
        asm volatile("" ::: "memory");
        if (kt + 2 < nkt) {
            stage_kv32(buf, kgp, vgp, kt + 2, wave, lane);
            asm volatile("s_waitcnt vmcnt(8)" ::: "memory");
        } else if (kt + 1 < nkt) {
            asm volatile("s_waitcnt vmcnt(0)" ::: "memory");
        }
        __builtin_amdgcn_s_barrier();
        asm volatile("" ::: "memory");
    }

    // ---- epilogue: distribute l_i (held at lane = qrow) to the C-layout rows, store
    float linv[16];
    #pragma unroll
    for (int r = 0; r < 16; ++r) {
        const int qr = (r & 3) + 8 * (r >> 2) + 4 * hi;
        linv[r] = 1.0f / __shfl(l_i, qr, 64);
    }
    u16* op = o + ((size_t)(b * AT_T + qb * 128 + wave * 32) * AT_H + h) * 128;
    #pragma unroll
    for (int dblk = 0; dblk < 4; ++dblk)
        #pragma unroll
        for (int r = 0; r < 16; ++r) {
            const int qr = (r & 3) + 8 * (r >> 2) + 4 * hi;
            op[(size_t)qr * 2048 + dblk * 32 + l32] = f2bf(Oacc[dblk][r] * linv[r]);
        }
}

// ---------------- launch ----------------
extern "C" void kernel_launch(void* const* d_in, const int* in_sizes, int n_in,
                              void* d_out, int out_size, void* d_ws, size_t ws_size,
                              hipStream_t stream) {
    const float* x    = (const float*)d_in[0];
    const float* w_aq = (const float*)d_in[1];
    const float* w_ak = (const float*)d_in[2];
    const float* w_av = (const float*)d_in[3];
    const float* w_ao = (const float*)d_in[4];
    float* outp = (float*)d_out;

    u16* ws   = (u16*)d_ws;
    u16* xb   = ws;                           // [4096][2048]      x, bf16
    u16* wqb  = xb   + (size_t)NROW * HD;     // [6144 n][2048 k]  (wq|wk|wv transposed)
    u16* waob = wqb  + (size_t)3 * HD * AT_M; // [2048 m][2048 hd] (w_ao^T)
    u16* qb   = waob + (size_t)HD * AT_M;     // [B,T,H,D] (then kb, vb contiguous)
    u16* kb   = qb   + (size_t)NROW * HD;
    u16* vb   = kb   + (size_t)NROW * HD;
    u16* vtb  = vb   + (size_t)NROW * HD;     // [B,H,D,T]
    u16* ob   = xb;                           // alias: xb dead after projections

    // 1) casts / transposes
    cast_bf16_k<<<(NROW * HD / 4 + 255) / 256, 256, 0, stream>>>(x, xb, NROW * HD / 4);
    dim3 tb(32, 8);
    tcast3_k<<<dim3(AT_D / 32, AT_M / 32, 48), tb, 0, stream>>>(w_aq, w_ak, w_av, wqb);
    tcast_k<<<dim3(AT_M / 32, HD / 32), tb, 0, stream>>>(w_ao, waob, HD, AT_M);

    // 2) fused QKV projection: 256x192 tile, grid 32x16 = 512 blocks
    gemm256_qkv_k<<<dim3(3 * HD / 192, NROW / 256), 512, 0, stream>>>(xb, wqb, qb, NROW, 3 * HD, AT_M);

    // 3) RoPE on q,k (q scaled by 1/128), short8-vectorized
    rope_k<<<(NROW * AT_H * 8 + 255) / 256, 256, 0, stream>>>(qb, kb, NROW * AT_H * 8);

    // 4) v -> [B,H,D,T]
    tbf16_k<<<dim3(HD / 32, AT_T / 32, AT_B), tb, 0, stream>>>(vb, vtb, AT_T, HD);

    // 5) attention v2 + XCD-locality block mapping (512 linear blocks)
    attn32_k<<<dim3(512, 1, 1), 256, 0, stream>>>(qb, kb, vtb, ob);

    // 6) output projection (fp32 out)
    gemm_bt_k<1><<<dim3(AT_M / 128, NROW / 128), 256, 0, stream>>>(ob, waob, outp, NROW, AT_M, HD);
}

// Round 10
// 369.092 us; speedup vs baseline: 1.0195x; 1.0195x over previous
//
#include <hip/hip_runtime.h>
#include <hip/hip_bf16.h>
#include <cmath>

typedef unsigned short u16;
typedef __attribute__((ext_vector_type(8))) short short8;
typedef __attribute__((ext_vector_type(4))) float f32x4;
typedef __attribute__((ext_vector_type(16))) float f32x16;
typedef __attribute__((ext_vector_type(4))) unsigned short u16x4;
typedef __attribute__((ext_vector_type(4))) unsigned int u32x4;

#define AT_B 2
#define AT_T 2048
#define AT_H 16
#define AT_D 128
#define AT_M 2048
#define NROW (AT_B*AT_T)   // 4096
#define HD   (AT_H*AT_D)   // 2048

__device__ __forceinline__ u16 f2bf(float f) {
    union { float f; unsigned u; } v; v.f = f;
    unsigned u = v.u;
    unsigned r = u + 0x7fffu + ((u >> 16) & 1u);
    return (u16)(r >> 16);
}
__device__ __forceinline__ float bf2f(u16 h) {
    union { unsigned u; float f; } v; v.u = ((unsigned)h) << 16;
    return v.f;
}
__device__ __forceinline__ unsigned pack_bf2(float a, float b) {
    __hip_bfloat162 t = __float22bfloat162_rn(make_float2(a, b));
    union { __hip_bfloat162 h; unsigned u; } v; v.h = t;
    return v.u;
}

// async global->LDS DMA, 16B per lane. LDS dest = wave-uniform base + lane*16.
__device__ __forceinline__ void gload16(const u16* g, u16* l) {
    __builtin_amdgcn_global_load_lds(
        (const __attribute__((address_space(1))) void*)g,
        (__attribute__((address_space(3))) void*)l, 16, 0, 0);
}

// ---------------- elementwise cast fp32 -> bf16 (vec4) ----------------
__global__ void cast_bf16_k(const float* __restrict__ in, u16* __restrict__ out, int n4) {
    int i = blockIdx.x * 256 + threadIdx.x;
    if (i >= n4) return;
    float4 v = ((const float4*)in)[i];
    u16x4 o;
    o.x = f2bf(v.x); o.y = f2bf(v.y); o.z = f2bf(v.z); o.w = f2bf(v.w);
    ((u16x4*)out)[i] = o;
}

// ------------- QKV weight transpose-cast: 3 weights in one launch -------------
__global__ void tcast3_k(const float* __restrict__ wq, const float* __restrict__ wk,
                         const float* __restrict__ wv, u16* __restrict__ out) {
    __shared__ float tile[32][33];
    int bx = blockIdx.x, by = blockIdx.y, bz = blockIdx.z;
    int which = bz >> 4, h = bz & 15;
    const float* ip = (which == 0 ? wq : which == 1 ? wk : wv) + (size_t)h * AT_M * AT_D;
    u16* op = out + ((size_t)which * AT_H + h) * AT_M * AT_D;
    int tx = threadIdx.x, ty = threadIdx.y;
    #pragma unroll
    for (int j = 0; j < 32; j += 8)
        tile[ty + j][tx] = ip[(size_t)(by * 32 + ty + j) * AT_D + bx * 32 + tx];
    __syncthreads();
    #pragma unroll
    for (int j = 0; j < 32; j += 8)
        op[(size_t)(bx * 32 + ty + j) * AT_M + by * 32 + tx] = f2bf(tile[tx][ty + j]);
}

// ------------- transpose-cast: in[R][C] fp32 -> out[C][R] bf16 (w_ao) -------------
__global__ void tcast_k(const float* __restrict__ in, u16* __restrict__ out, int R, int C) {
    __shared__ float tile[32][33];
    int bx = blockIdx.x, by = blockIdx.y;
    int tx = threadIdx.x, ty = threadIdx.y;
    #pragma unroll
    for (int j = 0; j < 32; j += 8)
        tile[ty + j][tx] = in[(size_t)(by * 32 + ty + j) * C + bx * 32 + tx];
    __syncthreads();
    #pragma unroll
    for (int j = 0; j < 32; j += 8)
        out[(size_t)(bx * 32 + ty + j) * R + by * 32 + tx] = f2bf(tile[tx][ty + j]);
}

// ------------- batched transpose bf16 -> bf16: in[bz][R][C] -> out[bz][C][R] -------------
__global__ void tbf16_k(const u16* __restrict__ in, u16* __restrict__ out, int R, int C) {
    __shared__ u16 tile[32][33];
    int bx = blockIdx.x, by = blockIdx.y, bz = blockIdx.z;
    const u16* ip = in + (size_t)bz * R * C;
    u16* op = out + (size_t)bz * R * C;
    int tx = threadIdx.x, ty = threadIdx.y;
    #pragma unroll
    for (int j = 0; j < 32; j += 8)
        tile[ty + j][tx] = ip[(size_t)(by * 32 + ty + j) * C + bx * 32 + tx];
    __syncthreads();
    #pragma unroll
    for (int j = 0; j < 32; j += 8)
        op[(size_t)(bx * 32 + ty + j) * R + by * 32 + tx] = tile[tx][ty + j];
}

// ---------------- RoPE in place, short8-vectorized (16B/lane); q scaled by 1/128 ----------------
__global__ void rope_k(u16* __restrict__ q, u16* __restrict__ k, int total8) {
    int i = blockIdx.x * 256 + threadIdx.x;
    if (i >= total8) return;
    const int dg = i & 7;
    const int rest = i >> 3;               // (b*T+t)*H + h
    const int t = (rest >> 4) & (AT_T - 1);
    const size_t base = (size_t)rest * 128 + dg * 8;
    short8 qe8 = *(const short8*)&q[base], qo8 = *(const short8*)&q[base + 64];
    short8 ke8 = *(const short8*)&k[base], ko8 = *(const short8*)&k[base + 64];
    short8 rqe, rqo, rke, rko;
    const float qs = 0.0078125f;  // 1/128, exact
    #pragma unroll
    for (int j = 0; j < 8; ++j) {
        const int d = dg * 8 + j;
        float freq = __expf(-(float)d * (9.210340371976184f / 64.0f)); // 10000^{-d/64}
        float s, c;
        sincosf((float)t * freq, &s, &c);
        float qe = bf2f((u16)qe8[j]), qo = bf2f((u16)qo8[j]);
        rqe[j] = (short)f2bf((qe * c - qo * s) * qs);
        rqo[j] = (short)f2bf((qe * s + qo * c) * qs);
        float ke = bf2f((u16)ke8[j]), ko = bf2f((u16)ko8[j]);
        rke[j] = (short)f2bf(ke * c - ko * s);
        rko[j] = (short)f2bf(ke * s + ko * c);
    }
    *(short8*)&q[base]      = rqe;
    *(short8*)&q[base + 64] = rqo;
    *(short8*)&k[base]      = rke;
    *(short8*)&k[base + 64] = rko;
}

// =================================================================================
// 256x192-tile QKV GEMM (proven R3 structure, 117.6 us / 876 TF), 512 threads.
// global_load_lds staging, involution chunk swizzle, dbuf LDS, counted vmcnt(7).
// =================================================================================
#define G_ASZ (256*64)
#define G_BSZ (192*64)
#define G_STRIDE (G_ASZ + G_BSZ)
__global__ __launch_bounds__(512, 2) void gemm256_qkv_k(
    const u16* __restrict__ A, const u16* __restrict__ Bt, u16* __restrict__ Cv,
    int M, int N, int K)
{
    __shared__ __align__(1024) u16 smem[2 * G_STRIDE];   // 112 KiB
    const int tid  = threadIdx.x;
    const int wave = tid >> 6, lane = tid & 63;
    const int quad = lane >> 4, l16 = lane & 15;
    const int wr = wave >> 2, wc = wave & 3;
    const int m0 = blockIdx.y * 256, n0 = blockIdx.x * 192;

    const int rl = lane >> 3;               // 0..7
    const int jc = (lane & 7) ^ rl;         // pre-swizzled source k-chunk
    const u16* ga = A  + (size_t)(m0 + wave * 8 + rl) * K + jc * 8;
    const u16* gb = Bt + (size_t)(n0 + wave * 8 + rl) * K + jc * 8;
    const int ldst = (wave * 64) * 8;

    f32x4 zero = {0.f, 0.f, 0.f, 0.f};
    f32x4 acc[8][3];
    #pragma unroll
    for (int i = 0; i < 8; i++)
        #pragma unroll
        for (int j = 0; j < 3; j++) acc[i][j] = zero;

    const int NT = K >> 6;

    {
        #pragma unroll
        for (int i = 0; i < 4; ++i) gload16(ga + (size_t)(i * 64) * K,      smem + i * 512 * 8 + ldst);
        #pragma unroll
        for (int i = 0; i < 3; ++i) gload16(gb + (size_t)(i * 64) * K,      smem + G_ASZ + i * 512 * 8 + ldst);
        #pragma unroll
        for (int i = 0; i < 4; ++i) gload16(ga + (size_t)(i * 64) * K + 64, smem + G_STRIDE + i * 512 * 8 + ldst);
        #pragma unroll
        for (int i = 0; i < 3; ++i) gload16(gb + (size_t)(i * 64) * K + 64, smem + G_STRIDE + G_ASZ + i * 512 * 8 + ldst);
    }
    asm volatile("s_waitcnt vmcnt(7)" ::: "memory");
    __builtin_amdgcn_s_barrier();
    asm volatile("" ::: "memory");

    const int arow = (wr * 128 + l16) * 64;
    const int brow = (wc * 48  + l16) * 64;
    const int rsw  = l16 & 7;

    for (int t = 0; t < NT; ++t) {
        const int boff = (t & 1) * G_STRIDE;
        const u16* as = smem + boff;
        const u16* bs = smem + boff + G_ASZ;
        #pragma unroll
        for (int ks = 0; ks < 2; ++ks) {
            const int ch = ((ks * 4 + quad) ^ rsw) * 8;
            short8 af[8], bfr[3];
            #pragma unroll
            for (int mf = 0; mf < 8; ++mf)
                af[mf] = *(const short8*)&as[arow + mf * (16 * 64) + ch];
            #pragma unroll
            for (int nf = 0; nf < 3; ++nf)
                bfr[nf] = *(const short8*)&bs[brow + nf * (16 * 64) + ch];
            #pragma unroll
            for (int mf = 0; mf < 8; ++mf)
                #pragma unroll
                for (int nf = 0; nf < 3; ++nf)
                    acc[mf][nf] = __builtin_amdgcn_mfma_f32_16x16x32_bf16(af[mf], bfr[nf], acc[mf][nf], 0, 0, 0);
        }
        if (t + 1 < NT) {
            asm volatile("s_waitcnt lgkmcnt(0)" ::: "memory");
            __builtin_amdgcn_s_barrier();
            asm volatile("" ::: "memory");
            if (t + 2 < NT) {
                const int kk = (t + 2) * 64;
                u16* asw = smem + boff;
                u16* bsw = smem + boff + G_ASZ;
                #pragma unroll
                for (int i = 0; i < 4; ++i)
                    gload16(ga + (size_t)(i * 64) * K + kk, asw + i * 512 * 8 + ldst);
                #pragma unroll
                for (int i = 0; i < 3; ++i)
                    gload16(gb + (size_t)(i * 64) * K + kk, bsw + i * 512 * 8 + ldst);
                asm volatile("s_waitcnt vmcnt(7)" ::: "memory");
            } else {
                asm volatile("s_waitcnt vmcnt(0)" ::: "memory");
            }
            __builtin_amdgcn_s_barrier();
            asm volatile("" ::: "memory");
        }
    }

    #pragma unroll
    for (int mf = 0; mf < 8; ++mf)
        #pragma unroll
        for (int nf = 0; nf < 3; ++nf) {
            int col = n0 + wc * 48 + nf * 16 + l16;
            size_t base = ((size_t)(col >> 11) * M) * 2048 + (col & 2047);
            #pragma unroll
            for (int r = 0; r < 4; ++r) {
                int row = m0 + wr * 128 + mf * 16 + quad * 4 + r;
                Cv[base + (size_t)row * 2048] = f2bf(acc[mf][nf][r]);
            }
        }
}

// ---------------- GEMM: C[M][N] = A[M][K] * Bt[N][K]^T  (bf16 in, fp32 acc) ----------------
template<int FP32OUT>
__global__ __launch_bounds__(256, 2) void gemm_bt_k(
    const u16* __restrict__ A, const u16* __restrict__ Bt, void* __restrict__ Cv,
    int M, int N, int K)
{
    __shared__ u16 As[128 * 64];
    __shared__ u16 Bs[128 * 64];
    const int tid = threadIdx.x, wave = tid >> 6, lane = tid & 63;
    const int quad = lane >> 4, l16 = lane & 15;
    const int m0 = blockIdx.y * 128, n0 = blockIdx.x * 128;
    const int mw = (wave & 1) * 64, nw = (wave >> 1) * 64;

    f32x4 zero = {0.f, 0.f, 0.f, 0.f};
    f32x4 acc[4][4];
    #pragma unroll
    for (int i = 0; i < 4; i++)
        #pragma unroll
        for (int j = 0; j < 4; j++) acc[i][j] = zero;

    const int sr = tid >> 3;          // 0..31
    const int sj = tid & 7;           // k-chunk
    const u16* ga0 = A  + (size_t)(m0 + sr) * K + sj * 8;
    const u16* gb0 = Bt + (size_t)(n0 + sr) * K + sj * 8;
    int woff[4];
    #pragma unroll
    for (int it = 0; it < 4; ++it) {
        int r = it * 32 + sr;
        woff[it] = r * 64 + ((sj ^ (r & 7)) * 8);
    }

    short8 abuf[4], bbuf[4];
    #pragma unroll
    for (int it = 0; it < 4; ++it) {
        abuf[it] = *(const short8*)(ga0 + (size_t)(it * 32) * K);
        bbuf[it] = *(const short8*)(gb0 + (size_t)(it * 32) * K);
    }
    #pragma unroll
    for (int it = 0; it < 4; ++it) {
        *(short8*)&As[woff[it]] = abuf[it];
        *(short8*)&Bs[woff[it]] = bbuf[it];
    }
    __syncthreads();

    const int rsw = l16 & 7;

    for (int kk = 0; kk < K; kk += 64) {
        const bool pre = (kk + 64 < K);
        if (pre) {
            #pragma unroll
            for (int it = 0; it < 4; ++it) {
                abuf[it] = *(const short8*)(ga0 + (size_t)(it * 32) * K + (kk + 64));
                bbuf[it] = *(const short8*)(gb0 + (size_t)(it * 32) * K + (kk + 64));
            }
        }
        #pragma unroll
        for (int ks = 0; ks < 2; ks++) {
            const int ch = ((ks * 4 + quad) ^ rsw) * 8;
            short8 af[4], bfr[4];
            #pragma unroll
            for (int mf = 0; mf < 4; mf++)
                af[mf] = *(const short8*)&As[(mw + mf * 16 + l16) * 64 + ch];
            #pragma unroll
            for (int nf = 0; nf < 4; nf++)
                bfr[nf] = *(const short8*)&Bs[(nw + nf * 16 + l16) * 64 + ch];
            #pragma unroll
            for (int mf = 0; mf < 4; mf++)
                #pragma unroll
                for (int nf = 0; nf < 4; nf++)
                    acc[mf][nf] = __builtin_amdgcn_mfma_f32_16x16x32_bf16(af[mf], bfr[nf], acc[mf][nf], 0, 0, 0);
        }
        if (pre) {
            __syncthreads();
            #pragma unroll
            for (int it = 0; it < 4; ++it) {
                *(short8*)&As[woff[it]] = abuf[it];
                *(short8*)&Bs[woff[it]] = bbuf[it];
            }
            __syncthreads();
        }
    }

    #pragma unroll
    for (int mf = 0; mf < 4; mf++)
        #pragma unroll
        for (int nf = 0; nf < 4; nf++)
            #pragma unroll
            for (int r = 0; r < 4; r++) {
                int row = m0 + mw + mf * 16 + quad * 4 + r;
                int col = n0 + nw + nf * 16 + l16;
                if (FP32OUT) ((float*)Cv)[(size_t)row * N + col] = acc[mf][nf][r];
                else         ((u16*) Cv)[(size_t)row * N + col] = f2bf(acc[mf][nf][r]);
            }
}

// =================================================================================
// Flash attention v2: 32x32 MFMA, swapped QK^T (keys in registers), in-register
// softmax + permlane32_swap P-fragment build. 256 threads = 4 waves x 32 q-rows.
// R10: grid reverted to dim3(16,H,B) with (b&1) qb reversal (complementary pairing
// of co-resident blocks — R8's best-measured config; XCD remap refuted in R9).
// Added T5 s_setprio(1/0) around QK and PV MFMA clusters (m191: +4-7% attn).
// =================================================================================
__device__ __forceinline__ void stage_kv32(u16* dst, const u16* kgp, const u16* vgp,
                                           int kt, int wave, int lane) {
    #pragma unroll
    for (int i = 0; i < 4; ++i) {
        const int g = i * 4 + wave;
        const int krow = g * 4 + (lane >> 4);
        const int kc = (lane & 15) ^ (krow & 7);
        gload16(kgp + (size_t)(kt * 64 + krow) * 2048 + kc * 8, dst + g * 512);
        const int vrow = g * 8 + (lane >> 3);
        const int vc = (lane & 7) ^ (vrow & 7);
        gload16(vgp + (size_t)vrow * AT_T + kt * 64 + vc * 8, dst + 8192 + g * 512);
    }
}

__global__ __launch_bounds__(256, 2) void attn32_k(
    const u16* __restrict__ q, const u16* __restrict__ k,
    const u16* __restrict__ vt, u16* __restrict__ o)
{
    __shared__ __align__(1024) u16 smem[2 * 16384];   // dbuf x (Ks 16KB + Vs 16KB)
    const int tid = threadIdx.x, wave = tid >> 6, lane = tid & 63;
    const int l32 = lane & 31, hi = lane >> 5;
    const int h = blockIdx.y, b = blockIdx.z;
    const int qb = (b & 1) ? (15 - (int)blockIdx.x) : (int)blockIdx.x;
    const int nkt = 2 * qb + 2;

    const u16* kgp = k  + ((size_t)(b * AT_T) * AT_H + h) * 128;
    const u16* vgp = vt + ((size_t)(b * AT_H + h) * 128) * (size_t)AT_T;

    // Q in regs: qf[kc] = Q[qrow][d = kc*16 + hi*8 + (0..8)]  (B-frag for 32x32x16)
    short8 qf[8];
    {
        const u16* qp = q + ((size_t)(b * AT_T + qb * 128 + wave * 32 + l32) * AT_H + h) * 128 + hi * 8;
        #pragma unroll
        for (int kc = 0; kc < 8; ++kc)
            qf[kc] = *(const short8*)(qp + kc * 16);
    }

    const f32x16 z16 = {0.f,0.f,0.f,0.f,0.f,0.f,0.f,0.f,0.f,0.f,0.f,0.f,0.f,0.f,0.f,0.f};
    f32x16 Oacc[4];
    #pragma unroll
    for (int i = 0; i < 4; ++i) Oacc[i] = z16;
    float l_i = 0.f;

    // prologue: stage tiles 0 and 1, wait tile 0 (vmcnt(8) leaves tile1's 8 in flight)
    stage_kv32(smem,          kgp, vgp, 0, wave, lane);
    stage_kv32(smem + 16384,  kgp, vgp, 1, wave, lane);
    asm volatile("s_waitcnt vmcnt(8)" ::: "memory");
    __builtin_amdgcn_s_barrier();
    asm volatile("" ::: "memory");

    for (int kt = 0; kt < nkt; ++kt) {
        u16* buf = smem + (kt & 1) * 16384;
        const u16* Ks = buf;
        const u16* Vs = buf + 8192;
        const int lkey0 = kt * 64 - qb * 128;      // block-local key base (may be <0)
        const bool act = (lkey0 <= wave * 32 + 31); // wave-uniform skip of fully-masked tiles

        if (act) {
            // ---- QK^T: acc[kch][reg] = S[key][qrow=l32]; keys = (r&3)+8*(r>>2)+4*hi+32*kch
            f32x16 acc[2];
            acc[0] = z16; acc[1] = z16;
            __builtin_amdgcn_s_setprio(1);
            #pragma unroll
            for (int kch = 0; kch < 2; ++kch) {
                #pragma unroll
                for (int kc = 0; kc < 8; ++kc) {
                    const int row = kch * 32 + l32;
                    const int cc = (kc * 2 + hi) ^ (lane & 7);
                    short8 af = *(const short8*)&Ks[row * 128 + cc * 8];
                    acc[kch] = __builtin_amdgcn_mfma_f32_32x32x16_bf16(af, qf[kc], acc[kch], 0, 0, 0);
                }
            }
            __builtin_amdgcn_s_setprio(0);
            // ---- masked exp (max-free) + row-sum
            float rs = 0.f;
            #pragma unroll
            for (int kch = 0; kch < 2; ++kch)
                #pragma unroll
                for (int r = 0; r < 16; ++r) {
                    const int keyb = lkey0 + kch * 32 + (r & 3) + 8 * (r >> 2) + 4 * hi;
                    float sv = acc[kch][r];
                    sv = (keyb > wave * 32 + l32) ? -1e30f : sv;
                    const float e = __expf(sv);
                    acc[kch][r] = e;
                    rs += e;
                }
            rs += __shfl_xor(rs, 32, 64);   // lanes l and l+32 hold the same qrow
            l_i += rs;
            // ---- PV: per 16-key window, build P A-frag via cvt_pk + 2 permlane32_swap
            __builtin_amdgcn_s_setprio(1);
            #pragma unroll
            for (int w16 = 0; w16 < 4; ++w16) {
                const int ch = w16 >> 1, rb = (w16 & 1) * 8;
                unsigned A0 = pack_bf2(acc[ch][rb + 0], acc[ch][rb + 1]);
                unsigned A1 = pack_bf2(acc[ch][rb + 2], acc[ch][rb + 3]);
                unsigned B0 = pack_bf2(acc[ch][rb + 4], acc[ch][rb + 5]);
                unsigned B1 = pack_bf2(acc[ch][rb + 6], acc[ch][rb + 7]);
                asm volatile("v_permlane32_swap_b32 %0, %1" : "+v"(A0), "+v"(B0));
                asm volatile("v_permlane32_swap_b32 %0, %1" : "+v"(A1), "+v"(B1));
                union { u32x4 w; short8 s; } pa;
                pa.w.x = A0; pa.w.y = A1; pa.w.z = B0; pa.w.w = B1;
                #pragma unroll
                for (int dblk = 0; dblk < 4; ++dblk) {
                    const int rowv = dblk * 32 + l32;
                    const int cv = (w16 * 2 + hi) ^ (lane & 7);
                    short8 vf = *(const short8*)&Vs[rowv * 64 + cv * 8];
                    Oacc[dblk] = __builtin_amdgcn_mfma_f32_32x32x16_bf16(pa.s, vf, Oacc[dblk], 0, 0, 0);
                }
            }
            __builtin_amdgcn_s_setprio(0);
        }

        // ---- barrier pair with liveness-correct staging (R3 pattern, vmcnt(8))
        asm volatile("s_waitcnt lgkmcnt(0)" ::: "memory");
        __builtin_amdgcn_s_barrier();
        asm volatile("" ::: "memory");
        if (kt + 2 < nkt) {
            stage_kv32(buf, kgp, vgp, kt + 2, wave, lane);
            asm volatile("s_waitcnt vmcnt(8)" ::: "memory");
        } else if (kt + 1 < nkt) {
            asm volatile("s_waitcnt vmcnt(0)" ::: "memory");
        }
        __builtin_amdgcn_s_barrier();
        asm volatile("" ::: "memory");
    }

    // ---- epilogue: distribute l_i (held at lane = qrow) to the C-layout rows, store
    float linv[16];
    #pragma unroll
    for (int r = 0; r < 16; ++r) {
        const int qr = (r & 3) + 8 * (r >> 2) + 4 * hi;
        linv[r] = 1.0f / __shfl(l_i, qr, 64);
    }
    u16* op = o + ((size_t)(b * AT_T + qb * 128 + wave * 32) * AT_H + h) * 128;
    #pragma unroll
    for (int dblk = 0; dblk < 4; ++dblk)
        #pragma unroll
        for (int r = 0; r < 16; ++r) {
            const int qr = (r & 3) + 8 * (r >> 2) + 4 * hi;
            op[(size_t)qr * 2048 + dblk * 32 + l32] = f2bf(Oacc[dblk][r] * linv[r]);
        }
}

// ---------------- launch ----------------
extern "C" void kernel_launch(void* const* d_in, const int* in_sizes, int n_in,
                              void* d_out, int out_size, void* d_ws, size_t ws_size,
                              hipStream_t stream) {
    const float* x    = (const float*)d_in[0];
    const float* w_aq = (const float*)d_in[1];
    const float* w_ak = (const float*)d_in[2];
    const float* w_av = (const float*)d_in[3];
    const float* w_ao = (const float*)d_in[4];
    float* outp = (float*)d_out;

    u16* ws   = (u16*)d_ws;
    u16* xb   = ws;                           // [4096][2048]      x, bf16
    u16* wqb  = xb   + (size_t)NROW * HD;     // [6144 n][2048 k]  (wq|wk|wv transposed)
    u16* waob = wqb  + (size_t)3 * HD * AT_M; // [2048 m][2048 hd] (w_ao^T)
    u16* qb   = waob + (size_t)HD * AT_M;     // [B,T,H,D] (then kb, vb contiguous)
    u16* kb   = qb   + (size_t)NROW * HD;
    u16* vb   = kb   + (size_t)NROW * HD;
    u16* vtb  = vb   + (size_t)NROW * HD;     // [B,H,D,T]
    u16* ob   = xb;                           // alias: xb dead after projections

    // 1) casts / transposes
    cast_bf16_k<<<(NROW * HD / 4 + 255) / 256, 256, 0, stream>>>(x, xb, NROW * HD / 4);
    dim3 tb(32, 8);
    tcast3_k<<<dim3(AT_D / 32, AT_M / 32, 48), tb, 0, stream>>>(w_aq, w_ak, w_av, wqb);
    tcast_k<<<dim3(AT_M / 32, HD / 32), tb, 0, stream>>>(w_ao, waob, HD, AT_M);

    // 2) fused QKV projection: 256x192 tile, grid 32x16 = 512 blocks
    gemm256_qkv_k<<<dim3(3 * HD / 192, NROW / 256), 512, 0, stream>>>(xb, wqb, qb, NROW, 3 * HD, AT_M);

    // 3) RoPE on q,k (q scaled by 1/128), short8-vectorized
    rope_k<<<(NROW * AT_H * 8 + 255) / 256, 256, 0, stream>>>(qb, kb, NROW * AT_H * 8);

    // 4) v -> [B,H,D,T]
    tbf16_k<<<dim3(HD / 32, AT_T / 32, AT_B), tb, 0, stream>>>(vb, vtb, AT_T, HD);

    // 5) attention v2 (R8 grid + complementary qb pairing) + setprio on MFMA clusters
    attn32_k<<<dim3(16, AT_H, AT_B), 256, 0, stream>>>(qb, kb, vtb, ob);

    // 6) output projection (fp32 out)
    gemm_bt_k<1><<<dim3(AT_M / 128, NROW / 128), 256, 0, stream>>>(ob, waob, outp, NROW, AT_M, HD);
}

// Round 11
// 363.496 us; speedup vs baseline: 1.0352x; 1.0154x over previous
//
#include <hip/hip_runtime.h>
#include <hip/hip_bf16.h>
#include <cmath>

typedef unsigned short u16;
typedef __attribute__((ext_vector_type(8))) short short8;
typedef __attribute__((ext_vector_type(4))) float f32x4;
typedef __attribute__((ext_vector_type(16))) float f32x16;
typedef __attribute__((ext_vector_type(4))) unsigned short u16x4;
typedef __attribute__((ext_vector_type(4))) unsigned int u32x4;

#define AT_B 2
#define AT_T 2048
#define AT_H 16
#define AT_D 128
#define AT_M 2048
#define NROW (AT_B*AT_T)   // 4096
#define HD   (AT_H*AT_D)   // 2048

__device__ __forceinline__ u16 f2bf(float f) {
    union { float f; unsigned u; } v; v.f = f;
    unsigned u = v.u;
    unsigned r = u + 0x7fffu + ((u >> 16) & 1u);
    return (u16)(r >> 16);
}
__device__ __forceinline__ float bf2f(u16 h) {
    union { unsigned u; float f; } v; v.u = ((unsigned)h) << 16;
    return v.f;
}
__device__ __forceinline__ unsigned pack_bf2(float a, float b) {
    __hip_bfloat162 t = __float22bfloat162_rn(make_float2(a, b));
    union { __hip_bfloat162 h; unsigned u; } v; v.h = t;
    return v.u;
}

// async global->LDS DMA, 16B per lane. LDS dest = wave-uniform base + lane*16.
__device__ __forceinline__ void gload16(const u16* g, u16* l) {
    __builtin_amdgcn_global_load_lds(
        (const __attribute__((address_space(1))) void*)g,
        (__attribute__((address_space(3))) void*)l, 16, 0, 0);
}

// ---------------- elementwise cast fp32 -> bf16 (vec4) ----------------
__global__ void cast_bf16_k(const float* __restrict__ in, u16* __restrict__ out, int n4) {
    int i = blockIdx.x * 256 + threadIdx.x;
    if (i >= n4) return;
    float4 v = ((const float4*)in)[i];
    u16x4 o;
    o.x = f2bf(v.x); o.y = f2bf(v.y); o.z = f2bf(v.z); o.w = f2bf(v.w);
    ((u16x4*)out)[i] = o;
}

// ------------- QKV weight transpose-cast: 3 weights in one launch -------------
__global__ void tcast3_k(const float* __restrict__ wq, const float* __restrict__ wk,
                         const float* __restrict__ wv, u16* __restrict__ out) {
    __shared__ float tile[32][33];
    int bx = blockIdx.x, by = blockIdx.y, bz = blockIdx.z;
    int which = bz >> 4, h = bz & 15;
    const float* ip = (which == 0 ? wq : which == 1 ? wk : wv) + (size_t)h * AT_M * AT_D;
    u16* op = out + ((size_t)which * AT_H + h) * AT_M * AT_D;
    int tx = threadIdx.x, ty = threadIdx.y;
    #pragma unroll
    for (int j = 0; j < 32; j += 8)
        tile[ty + j][tx] = ip[(size_t)(by * 32 + ty + j) * AT_D + bx * 32 + tx];
    __syncthreads();
    #pragma unroll
    for (int j = 0; j < 32; j += 8)
        op[(size_t)(bx * 32 + ty + j) * AT_M + by * 32 + tx] = f2bf(tile[tx][ty + j]);
}

// ------------- transpose-cast: in[R][C] fp32 -> out[C][R] bf16 (w_ao) -------------
__global__ void tcast_k(const float* __restrict__ in, u16* __restrict__ out, int R, int C) {
    __shared__ float tile[32][33];
    int bx = blockIdx.x, by = blockIdx.y;
    int tx = threadIdx.x, ty = threadIdx.y;
    #pragma unroll
    for (int j = 0; j < 32; j += 8)
        tile[ty + j][tx] = in[(size_t)(by * 32 + ty + j) * C + bx * 32 + tx];
    __syncthreads();
    #pragma unroll
    for (int j = 0; j < 32; j += 8)
        out[(size_t)(bx * 32 + ty + j) * R + by * 32 + tx] = f2bf(tile[tx][ty + j]);
}

// ---------------- RoPE in place, short8-vectorized (16B/lane); q scaled by 1/128 ----------------
__global__ void rope_k(u16* __restrict__ q, u16* __restrict__ k, int total8) {
    int i = blockIdx.x * 256 + threadIdx.x;
    if (i >= total8) return;
    const int dg = i & 7;
    const int rest = i >> 3;               // (b*T+t)*H + h
    const int t = (rest >> 4) & (AT_T - 1);
    const size_t base = (size_t)rest * 128 + dg * 8;
    short8 qe8 = *(const short8*)&q[base], qo8 = *(const short8*)&q[base + 64];
    short8 ke8 = *(const short8*)&k[base], ko8 = *(const short8*)&k[base + 64];
    short8 rqe, rqo, rke, rko;
    const float qs = 0.0078125f;  // 1/128, exact
    #pragma unroll
    for (int j = 0; j < 8; ++j) {
        const int d = dg * 8 + j;
        float freq = __expf(-(float)d * (9.210340371976184f / 64.0f)); // 10000^{-d/64}
        float s, c;
        sincosf((float)t * freq, &s, &c);
        float qe = bf2f((u16)qe8[j]), qo = bf2f((u16)qo8[j]);
        rqe[j] = (short)f2bf((qe * c - qo * s) * qs);
        rqo[j] = (short)f2bf((qe * s + qo * c) * qs);
        float ke = bf2f((u16)ke8[j]), ko = bf2f((u16)ko8[j]);
        rke[j] = (short)f2bf(ke * c - ko * s);
        rko[j] = (short)f2bf(ke * s + ko * c);
    }
    *(short8*)&q[base]      = rqe;
    *(short8*)&q[base + 64] = rqo;
    *(short8*)&k[base]      = rke;
    *(short8*)&k[base + 64] = rko;
}

// =================================================================================
// 256x192-tile QKV GEMM (proven R3 structure, 876 TF), 512 threads.
// global_load_lds staging, involution chunk swizzle, dbuf LDS, counted vmcnt(7).
// R11: v-segment written DIRECTLY TRANSPOSED to [B,H,D,T] (tbf16_k kernel deleted).
// The 4 acc r-values are 4 consecutive tokens at fixed (h,d) -> one aligned 8-byte
// ushort4 store per (mf,nf). col-segment branch is lane-uniform (16-col groups
// never straddle the 2048-aligned segment boundaries).
// =================================================================================
#define G_ASZ (256*64)
#define G_BSZ (192*64)
#define G_STRIDE (G_ASZ + G_BSZ)
__global__ __launch_bounds__(512, 2) void gemm256_qkv_k(
    const u16* __restrict__ A, const u16* __restrict__ Bt, u16* __restrict__ Cv,
    u16* __restrict__ Vt, int M, int N, int K)
{
    __shared__ __align__(1024) u16 smem[2 * G_STRIDE];   // 112 KiB
    const int tid  = threadIdx.x;
    const int wave = tid >> 6, lane = tid & 63;
    const int quad = lane >> 4, l16 = lane & 15;
    const int wr = wave >> 2, wc = wave & 3;
    const int m0 = blockIdx.y * 256, n0 = blockIdx.x * 192;

    const int rl = lane >> 3;               // 0..7
    const int jc = (lane & 7) ^ rl;         // pre-swizzled source k-chunk
    const u16* ga = A  + (size_t)(m0 + wave * 8 + rl) * K + jc * 8;
    const u16* gb = Bt + (size_t)(n0 + wave * 8 + rl) * K + jc * 8;
    const int ldst = (wave * 64) * 8;

    f32x4 zero = {0.f, 0.f, 0.f, 0.f};
    f32x4 acc[8][3];
    #pragma unroll
    for (int i = 0; i < 8; i++)
        #pragma unroll
        for (int j = 0; j < 3; j++) acc[i][j] = zero;

    const int NT = K >> 6;

    {
        #pragma unroll
        for (int i = 0; i < 4; ++i) gload16(ga + (size_t)(i * 64) * K,      smem + i * 512 * 8 + ldst);
        #pragma unroll
        for (int i = 0; i < 3; ++i) gload16(gb + (size_t)(i * 64) * K,      smem + G_ASZ + i * 512 * 8 + ldst);
        #pragma unroll
        for (int i = 0; i < 4; ++i) gload16(ga + (size_t)(i * 64) * K + 64, smem + G_STRIDE + i * 512 * 8 + ldst);
        #pragma unroll
        for (int i = 0; i < 3; ++i) gload16(gb + (size_t)(i * 64) * K + 64, smem + G_STRIDE + G_ASZ + i * 512 * 8 + ldst);
    }
    asm volatile("s_waitcnt vmcnt(7)" ::: "memory");
    __builtin_amdgcn_s_barrier();
    asm volatile("" ::: "memory");

    const int arow = (wr * 128 + l16) * 64;
    const int brow = (wc * 48  + l16) * 64;
    const int rsw  = l16 & 7;

    for (int t = 0; t < NT; ++t) {
        const int boff = (t & 1) * G_STRIDE;
        const u16* as = smem + boff;
        const u16* bs = smem + boff + G_ASZ;
        #pragma unroll
        for (int ks = 0; ks < 2; ++ks) {
            const int ch = ((ks * 4 + quad) ^ rsw) * 8;
            short8 af[8], bfr[3];
            #pragma unroll
            for (int mf = 0; mf < 8; ++mf)
                af[mf] = *(const short8*)&as[arow + mf * (16 * 64) + ch];
            #pragma unroll
            for (int nf = 0; nf < 3; ++nf)
                bfr[nf] = *(const short8*)&bs[brow + nf * (16 * 64) + ch];
            #pragma unroll
            for (int mf = 0; mf < 8; ++mf)
                #pragma unroll
                for (int nf = 0; nf < 3; ++nf)
                    acc[mf][nf] = __builtin_amdgcn_mfma_f32_16x16x32_bf16(af[mf], bfr[nf], acc[mf][nf], 0, 0, 0);
        }
        if (t + 1 < NT) {
            asm volatile("s_waitcnt lgkmcnt(0)" ::: "memory");
            __builtin_amdgcn_s_barrier();
            asm volatile("" ::: "memory");
            if (t + 2 < NT) {
                const int kk = (t + 2) * 64;
                u16* asw = smem + boff;
                u16* bsw = smem + boff + G_ASZ;
                #pragma unroll
                for (int i = 0; i < 4; ++i)
                    gload16(ga + (size_t)(i * 64) * K + kk, asw + i * 512 * 8 + ldst);
                #pragma unroll
                for (int i = 0; i < 3; ++i)
                    gload16(gb + (size_t)(i * 64) * K + kk, bsw + i * 512 * 8 + ldst);
                asm volatile("s_waitcnt vmcnt(7)" ::: "memory");
            } else {
                asm volatile("s_waitcnt vmcnt(0)" ::: "memory");
            }
            __builtin_amdgcn_s_barrier();
            asm volatile("" ::: "memory");
        }
    }

    // epilogue: q|k segmented bf16 store; v stored TRANSPOSED to [B,H,D,T]
    #pragma unroll
    for (int mf = 0; mf < 8; ++mf)
        #pragma unroll
        for (int nf = 0; nf < 3; ++nf) {
            const int col = n0 + wc * 48 + nf * 16 + l16;
            const int row0 = m0 + wr * 128 + mf * 16 + quad * 4;
            if (col < 4096) {   // lane-uniform per (mf,nf)
                size_t base = ((size_t)(col >> 11) * M) * 2048 + (col & 2047);
                #pragma unroll
                for (int r = 0; r < 4; ++r)
                    Cv[base + (size_t)(row0 + r) * 2048] = f2bf(acc[mf][nf][r]);
            } else {
                const int c2 = col & 2047;          // h*128 + d
                const int bb = row0 >> 11, t0 = row0 & 2047;
                u16x4 pk;
                pk.x = f2bf(acc[mf][nf][0]); pk.y = f2bf(acc[mf][nf][1]);
                pk.z = f2bf(acc[mf][nf][2]); pk.w = f2bf(acc[mf][nf][3]);
                *(u16x4*)&Vt[((size_t)(bb * AT_H + (c2 >> 7)) * 128 + (c2 & 127)) * (size_t)AT_T + t0] = pk;
            }
        }
}

// ---------------- GEMM: C[M][N] = A[M][K] * Bt[N][K]^T  (bf16 in, fp32 acc) ----------------
template<int FP32OUT>
__global__ __launch_bounds__(256, 2) void gemm_bt_k(
    const u16* __restrict__ A, const u16* __restrict__ Bt, void* __restrict__ Cv,
    int M, int N, int K)
{
    __shared__ u16 As[128 * 64];
    __shared__ u16 Bs[128 * 64];
    const int tid = threadIdx.x, wave = tid >> 6, lane = tid & 63;
    const int quad = lane >> 4, l16 = lane & 15;
    const int m0 = blockIdx.y * 128, n0 = blockIdx.x * 128;
    const int mw = (wave & 1) * 64, nw = (wave >> 1) * 64;

    f32x4 zero = {0.f, 0.f, 0.f, 0.f};
    f32x4 acc[4][4];
    #pragma unroll
    for (int i = 0; i < 4; i++)
        #pragma unroll
        for (int j = 0; j < 4; j++) acc[i][j] = zero;

    const int sr = tid >> 3;          // 0..31
    const int sj = tid & 7;           // k-chunk
    const u16* ga0 = A  + (size_t)(m0 + sr) * K + sj * 8;
    const u16* gb0 = Bt + (size_t)(n0 + sr) * K + sj * 8;
    int woff[4];
    #pragma unroll
    for (int it = 0; it < 4; ++it) {
        int r = it * 32 + sr;
        woff[it] = r * 64 + ((sj ^ (r & 7)) * 8);
    }

    short8 abuf[4], bbuf[4];
    #pragma unroll
    for (int it = 0; it < 4; ++it) {
        abuf[it] = *(const short8*)(ga0 + (size_t)(it * 32) * K);
        bbuf[it] = *(const short8*)(gb0 + (size_t)(it * 32) * K);
    }
    #pragma unroll
    for (int it = 0; it < 4; ++it) {
        *(short8*)&As[woff[it]] = abuf[it];
        *(short8*)&Bs[woff[it]] = bbuf[it];
    }
    __syncthreads();

    const int rsw = l16 & 7;

    for (int kk = 0; kk < K; kk += 64) {
        const bool pre = (kk + 64 < K);
        if (pre) {
            #pragma unroll
            for (int it = 0; it < 4; ++it) {
                abuf[it] = *(const short8*)(ga0 + (size_t)(it * 32) * K + (kk + 64));
                bbuf[it] = *(const short8*)(gb0 + (size_t)(it * 32) * K + (kk + 64));
            }
        }
        #pragma unroll
        for (int ks = 0; ks < 2; ks++) {
            const int ch = ((ks * 4 + quad) ^ rsw) * 8;
            short8 af[4], bfr[4];
            #pragma unroll
            for (int mf = 0; mf < 4; mf++)
                af[mf] = *(const short8*)&As[(mw + mf * 16 + l16) * 64 + ch];
            #pragma unroll
            for (int nf = 0; nf < 4; nf++)
                bfr[nf] = *(const short8*)&Bs[(nw + nf * 16 + l16) * 64 + ch];
            #pragma unroll
            for (int mf = 0; mf < 4; mf++)
                #pragma unroll
                for (int nf = 0; nf < 4; nf++)
                    acc[mf][nf] = __builtin_amdgcn_mfma_f32_16x16x32_bf16(af[mf], bfr[nf], acc[mf][nf], 0, 0, 0);
        }
        if (pre) {
            __syncthreads();
            #pragma unroll
            for (int it = 0; it < 4; ++it) {
                *(short8*)&As[woff[it]] = abuf[it];
                *(short8*)&Bs[woff[it]] = bbuf[it];
            }
            __syncthreads();
        }
    }

    #pragma unroll
    for (int mf = 0; mf < 4; mf++)
        #pragma unroll
        for (int nf = 0; nf < 4; nf++)
            #pragma unroll
            for (int r = 0; r < 4; r++) {
                int row = m0 + mw + mf * 16 + quad * 4 + r;
                int col = n0 + nw + nf * 16 + l16;
                if (FP32OUT) ((float*)Cv)[(size_t)row * N + col] = acc[mf][nf][r];
                else         ((u16*) Cv)[(size_t)row * N + col] = f2bf(acc[mf][nf][r]);
            }
}

// =================================================================================
// Flash attention v2: 32x32 MFMA, swapped QK^T (keys in registers), in-register
// softmax + permlane32_swap P-fragment build. 256 threads = 4 waves x 32 q-rows.
// Grid dim3(16,H,B) with (b&1) qb reversal (R8 best-measured). setprio on MFMA.
// =================================================================================
__device__ __forceinline__ void stage_kv32(u16* dst, const u16* kgp, const u16* vgp,
                                           int kt, int wave, int lane) {
    #pragma unroll
    for (int i = 0; i < 4; ++i) {
        const int g = i * 4 + wave;
        const int krow = g * 4 + (lane >> 4);
        const int kc = (lane & 15) ^ (krow & 7);
        gload16(kgp + (size_t)(kt * 64 + krow) * 2048 + kc * 8, dst + g * 512);
        const int vrow = g * 8 + (lane >> 3);
        const int vc = (lane & 7) ^ (vrow & 7);
        gload16(vgp + (size_t)vrow * AT_T + kt * 64 + vc * 8, dst + 8192 + g * 512);
    }
}

__global__ __launch_bounds__(256, 2) void attn32_k(
    const u16* __restrict__ q, const u16* __restrict__ k,
    const u16* __restrict__ vt, u16* __restrict__ o)
{
    __shared__ __align__(1024) u16 smem[2 * 16384];   // dbuf x (Ks 16KB + Vs 16KB)
    const int tid = threadIdx.x, wave = tid >> 6, lane = tid & 63;
    const int l32 = lane & 31, hi = lane >> 5;
    const int h = blockIdx.y, b = blockIdx.z;
    const int qb = (b & 1) ? (15 - (int)blockIdx.x) : (int)blockIdx.x;
    const int nkt = 2 * qb + 2;

    const u16* kgp = k  + ((size_t)(b * AT_T) * AT_H + h) * 128;
    const u16* vgp = vt + ((size_t)(b * AT_H + h) * 128) * (size_t)AT_T;

    // Q in regs: qf[kc] = Q[qrow][d = kc*16 + hi*8 + (0..8)]  (B-frag for 32x32x16)
    short8 qf[8];
    {
        const u16* qp = q + ((size_t)(b * AT_T + qb * 128 + wave * 32 + l32) * AT_H + h) * 128 + hi * 8;
        #pragma unroll
        for (int kc = 0; kc < 8; ++kc)
            qf[kc] = *(const short8*)(qp + kc * 16);
    }

    const f32x16 z16 = {0.f,0.f,0.f,0.f,0.f,0.f,0.f,0.f,0.f,0.f,0.f,0.f,0.f,0.f,0.f,0.f};
    f32x16 Oacc[4];
    #pragma unroll
    for (int i = 0; i < 4; ++i) Oacc[i] = z16;
    float l_i = 0.f;

    // prologue: stage tiles 0 and 1, wait tile 0 (vmcnt(8) leaves tile1's 8 in flight)
    stage_kv32(smem,          kgp, vgp, 0, wave, lane);
    stage_kv32(smem + 16384,  kgp, vgp, 1, wave, lane);
    asm volatile("s_waitcnt vmcnt(8)" ::: "memory");
    __builtin_amdgcn_s_barrier();
    asm volatile("" ::: "memory");

    for (int kt = 0; kt < nkt; ++kt) {
        u16* buf = smem + (kt & 1) * 16384;
        const u16* Ks = buf;
        const u16* Vs = buf + 8192;
        const int lkey0 = kt * 64 - qb * 128;      // block-local key base (may be <0)
        const bool act = (lkey0 <= wave * 32 + 31); // wave-uniform skip of fully-masked tiles

        if (act) {
            // ---- QK^T: acc[kch][reg] = S[key][qrow=l32]; keys = (r&3)+8*(r>>2)+4*hi+32*kch
            f32x16 acc[2];
            acc[0] = z16; acc[1] = z16;
            __builtin_amdgcn_s_setprio(1);
            #pragma unroll
            for (int kch = 0; kch < 2; ++kch) {
                #pragma unroll
                for (int kc = 0; kc < 8; ++kc) {
                    const int row = kch * 32 + l32;
                    const int cc = (kc * 2 + hi) ^ (lane & 7);
                    short8 af = *(const short8*)&Ks[row * 128 + cc * 8];
                    acc[kch] = __builtin_amdgcn_mfma_f32_32x32x16_bf16(af, qf[kc], acc[kch], 0, 0, 0);
                }
            }
            __builtin_amdgcn_s_setprio(0);
            // ---- masked exp (max-free) + row-sum
            float rs = 0.f;
            #pragma unroll
            for (int kch = 0; kch < 2; ++kch)
                #pragma unroll
                for (int r = 0; r < 16; ++r) {
                    const int keyb = lkey0 + kch * 32 + (r & 3) + 8 * (r >> 2) + 4 * hi;
                    float sv = acc[kch][r];
                    sv = (keyb > wave * 32 + l32) ? -1e30f : sv;
                    const float e = __expf(sv);
                    acc[kch][r] = e;
                    rs += e;
                }
            rs += __shfl_xor(rs, 32, 64);   // lanes l and l+32 hold the same qrow
            l_i += rs;
            // ---- PV: per 16-key window, build P A-frag via cvt_pk + 2 permlane32_swap
            __builtin_amdgcn_s_setprio(1);
            #pragma unroll
            for (int w16 = 0; w16 < 4; ++w16) {
                const int ch = w16 >> 1, rb = (w16 & 1) * 8;
                unsigned A0 = pack_bf2(acc[ch][rb + 0], acc[ch][rb + 1]);
                unsigned A1 = pack_bf2(acc[ch][rb + 2], acc[ch][rb + 3]);
                unsigned B0 = pack_bf2(acc[ch][rb + 4], acc[ch][rb + 5]);
                unsigned B1 = pack_bf2(acc[ch][rb + 6], acc[ch][rb + 7]);
                asm volatile("v_permlane32_swap_b32 %0, %1" : "+v"(A0), "+v"(B0));
                asm volatile("v_permlane32_swap_b32 %0, %1" : "+v"(A1), "+v"(B1));
                union { u32x4 w; short8 s; } pa;
                pa.w.x = A0; pa.w.y = A1; pa.w.z = B0; pa.w.w = B1;
                #pragma unroll
                for (int dblk = 0; dblk < 4; ++dblk) {
                    const int rowv = dblk * 32 + l32;
                    const int cv = (w16 * 2 + hi) ^ (lane & 7);
                    short8 vf = *(const short8*)&Vs[rowv * 64 + cv * 8];
                    Oacc[dblk] = __builtin_amdgcn_mfma_f32_32x32x16_bf16(pa.s, vf, Oacc[dblk], 0, 0, 0);
                }
            }
            __builtin_amdgcn_s_setprio(0);
        }

        // ---- barrier pair with liveness-correct staging (R3 pattern, vmcnt(8))
        asm volatile("s_waitcnt lgkmcnt(0)" ::: "memory");
        __builtin_amdgcn_s_barrier();
        asm volatile("" ::: "memory");
        if (kt + 2 < nkt) {
            stage_kv32(buf, kgp, vgp, kt + 2, wave, lane);
            asm volatile("s_waitcnt vmcnt(8)" ::: "memory");
        } else if (kt + 1 < nkt) {
            asm volatile("s_waitcnt vmcnt(0)" ::: "memory");
        }
        __builtin_amdgcn_s_barrier();
        asm volatile("" ::: "memory");
    }

    // ---- epilogue: distribute l_i (held at lane = qrow) to the C-layout rows, store
    float linv[16];
    #pragma unroll
    for (int r = 0; r < 16; ++r) {
        const int qr = (r & 3) + 8 * (r >> 2) + 4 * hi;
        linv[r] = 1.0f / __shfl(l_i, qr, 64);
    }
    u16* op = o + ((size_t)(b * AT_T + qb * 128 + wave * 32) * AT_H + h) * 128;
    #pragma unroll
    for (int dblk = 0; dblk < 4; ++dblk)
        #pragma unroll
        for (int r = 0; r < 16; ++r) {
            const int qr = (r & 3) + 8 * (r >> 2) + 4 * hi;
            op[(size_t)qr * 2048 + dblk * 32 + l32] = f2bf(Oacc[dblk][r] * linv[r]);
        }
}

// ---------------- launch ----------------
extern "C" void kernel_launch(void* const* d_in, const int* in_sizes, int n_in,
                              void* d_out, int out_size, void* d_ws, size_t ws_size,
                              hipStream_t stream) {
    const float* x    = (const float*)d_in[0];
    const float* w_aq = (const float*)d_in[1];
    const float* w_ak = (const float*)d_in[2];
    const float* w_av = (const float*)d_in[3];
    const float* w_ao = (const float*)d_in[4];
    float* outp = (float*)d_out;

    u16* ws   = (u16*)d_ws;
    u16* xb   = ws;                           // [4096][2048]      x, bf16
    u16* wqb  = xb   + (size_t)NROW * HD;     // [6144 n][2048 k]  (wq|wk|wv transposed)
    u16* waob = wqb  + (size_t)3 * HD * AT_M; // [2048 m][2048 hd] (w_ao^T)
    u16* qb   = waob + (size_t)HD * AT_M;     // [B,T,H,D] (then kb contiguous)
    u16* kb   = qb   + (size_t)NROW * HD;
    u16* vb   = kb   + (size_t)NROW * HD;     // unused (v written transposed directly)
    u16* vtb  = vb   + (size_t)NROW * HD;     // [B,H,D,T]
    u16* ob   = xb;                           // alias: xb dead after projections

    // 1) casts / transposes
    cast_bf16_k<<<(NROW * HD / 4 + 255) / 256, 256, 0, stream>>>(x, xb, NROW * HD / 4);
    dim3 tb(32, 8);
    tcast3_k<<<dim3(AT_D / 32, AT_M / 32, 48), tb, 0, stream>>>(w_aq, w_ak, w_av, wqb);
    tcast_k<<<dim3(AT_M / 32, HD / 32), tb, 0, stream>>>(w_ao, waob, HD, AT_M);

    // 2) fused QKV projection; v written directly as [B,H,D,T] (tbf16 eliminated)
    gemm256_qkv_k<<<dim3(3 * HD / 192, NROW / 256), 512, 0, stream>>>(xb, wqb, qb, vtb, NROW, 3 * HD, AT_M);

    // 3) RoPE on q,k (q scaled by 1/128), short8-vectorized
    rope_k<<<(NROW * AT_H * 8 + 255) / 256, 256, 0, stream>>>(qb, kb, NROW * AT_H * 8);

    // 4) attention v2 (swapped-QK 32x32, in-register softmax, permlane P-frags)
    attn32_k<<<dim3(16, AT_H, AT_B), 256, 0, stream>>>(qb, kb, vtb, ob);

    // 5) output projection (fp32 out)
    gemm_bt_k<1><<<dim3(AT_M / 128, NROW / 128), 256, 0, stream>>>(ob, waob, outp, NROW, AT_M, HD);
}

// Round 12
// 361.183 us; speedup vs baseline: 1.0418x; 1.0064x over previous
//
#include <hip/hip_runtime.h>
#include <hip/hip_bf16.h>
#include <cmath>

typedef unsigned short u16;
typedef __attribute__((ext_vector_type(8))) short short8;
typedef __attribute__((ext_vector_type(4))) float f32x4;
typedef __attribute__((ext_vector_type(16))) float f32x16;
typedef __attribute__((ext_vector_type(4))) unsigned short u16x4;
typedef __attribute__((ext_vector_type(4))) unsigned int u32x4;

#define AT_B 2
#define AT_T 2048
#define AT_H 16
#define AT_D 128
#define AT_M 2048
#define NROW (AT_B*AT_T)   // 4096
#define HD   (AT_H*AT_D)   // 2048

__device__ __forceinline__ u16 f2bf(float f) {
    union { float f; unsigned u; } v; v.f = f;
    unsigned u = v.u;
    unsigned r = u + 0x7fffu + ((u >> 16) & 1u);
    return (u16)(r >> 16);
}
__device__ __forceinline__ float bf2f(u16 h) {
    union { unsigned u; float f; } v; v.u = ((unsigned)h) << 16;
    return v.f;
}
__device__ __forceinline__ unsigned pack_bf2(float a, float b) {
    __hip_bfloat162 t = __float22bfloat162_rn(make_float2(a, b));
    union { __hip_bfloat162 h; unsigned u; } v; v.h = t;
    return v.u;
}

// async global->LDS DMA, 16B per lane. LDS dest = wave-uniform base + lane*16.
__device__ __forceinline__ void gload16(const u16* g, u16* l) {
    __builtin_amdgcn_global_load_lds(
        (const __attribute__((address_space(1))) void*)g,
        (__attribute__((address_space(3))) void*)l, 16, 0, 0);
}

// ---------------- elementwise cast fp32 -> bf16 (vec4) ----------------
__global__ void cast_bf16_k(const float* __restrict__ in, u16* __restrict__ out, int n4) {
    int i = blockIdx.x * 256 + threadIdx.x;
    if (i >= n4) return;
    float4 v = ((const float4*)in)[i];
    u16x4 o;
    o.x = f2bf(v.x); o.y = f2bf(v.y); o.z = f2bf(v.z); o.w = f2bf(v.w);
    ((u16x4*)out)[i] = o;
}

// ------------- QKV weight transpose-cast: 3 weights in one launch -------------
__global__ void tcast3_k(const float* __restrict__ wq, const float* __restrict__ wk,
                         const float* __restrict__ wv, u16* __restrict__ out) {
    __shared__ float tile[32][33];
    int bx = blockIdx.x, by = blockIdx.y, bz = blockIdx.z;
    int which = bz >> 4, h = bz & 15;
    const float* ip = (which == 0 ? wq : which == 1 ? wk : wv) + (size_t)h * AT_M * AT_D;
    u16* op = out + ((size_t)which * AT_H + h) * AT_M * AT_D;
    int tx = threadIdx.x, ty = threadIdx.y;
    #pragma unroll
    for (int j = 0; j < 32; j += 8)
        tile[ty + j][tx] = ip[(size_t)(by * 32 + ty + j) * AT_D + bx * 32 + tx];
    __syncthreads();
    #pragma unroll
    for (int j = 0; j < 32; j += 8)
        op[(size_t)(bx * 32 + ty + j) * AT_M + by * 32 + tx] = f2bf(tile[tx][ty + j]);
}

// ------------- transpose-cast: in[R][C] fp32 -> out[C][R] bf16 (w_ao) -------------
__global__ void tcast_k(const float* __restrict__ in, u16* __restrict__ out, int R, int C) {
    __shared__ float tile[32][33];
    int bx = blockIdx.x, by = blockIdx.y;
    int tx = threadIdx.x, ty = threadIdx.y;
    #pragma unroll
    for (int j = 0; j < 32; j += 8)
        tile[ty + j][tx] = in[(size_t)(by * 32 + ty + j) * C + bx * 32 + tx];
    __syncthreads();
    #pragma unroll
    for (int j = 0; j < 32; j += 8)
        out[(size_t)(bx * 32 + ty + j) * R + by * 32 + tx] = f2bf(tile[tx][ty + j]);
}

// ---------------- RoPE in place, short8-vectorized (16B/lane); q scaled by 1/128 ----------------
__global__ void rope_k(u16* __restrict__ q, u16* __restrict__ k, int total8) {
    int i = blockIdx.x * 256 + threadIdx.x;
    if (i >= total8) return;
    const int dg = i & 7;
    const int rest = i >> 3;               // (b*T+t)*H + h
    const int t = (rest >> 4) & (AT_T - 1);
    const size_t base = (size_t)rest * 128 + dg * 8;
    short8 qe8 = *(const short8*)&q[base], qo8 = *(const short8*)&q[base + 64];
    short8 ke8 = *(const short8*)&k[base], ko8 = *(const short8*)&k[base + 64];
    short8 rqe, rqo, rke, rko;
    const float qs = 0.0078125f;  // 1/128, exact
    #pragma unroll
    for (int j = 0; j < 8; ++j) {
        const int d = dg * 8 + j;
        float freq = __expf(-(float)d * (9.210340371976184f / 64.0f)); // 10000^{-d/64}
        float s, c;
        sincosf((float)t * freq, &s, &c);
        float qe = bf2f((u16)qe8[j]), qo = bf2f((u16)qo8[j]);
        rqe[j] = (short)f2bf((qe * c - qo * s) * qs);
        rqo[j] = (short)f2bf((qe * s + qo * c) * qs);
        float ke = bf2f((u16)ke8[j]), ko = bf2f((u16)ko8[j]);
        rke[j] = (short)f2bf(ke * c - ko * s);
        rko[j] = (short)f2bf(ke * s + ko * c);
    }
    *(short8*)&q[base]      = rqe;
    *(short8*)&q[base + 64] = rqo;
    *(short8*)&k[base]      = rke;
    *(short8*)&k[base + 64] = rko;
}

// =================================================================================
// 256x192-tile QKV GEMM (R3 structure), 512 threads. global_load_lds staging,
// involution chunk swizzle, dbuf LDS, counted vmcnt(7).
// R12: v-segment transposed to [B,H,D,T] THROUGH LDS (coalesced 16B stores) —
// fixes R11's 4096B-stride 8B scatter (+20us). LDS tile [192 cols][264 rows pad]
// = 101 KB, reuses smem; only buf0 region touched (buf0 reads retire at the
// t=NT-2 barrier; final K-tile reads buf1 only) -> one __syncthreads suffices.
// =================================================================================
#define G_ASZ (256*64)
#define G_BSZ (192*64)
#define G_STRIDE (G_ASZ + G_BSZ)
__global__ __launch_bounds__(512, 2) void gemm256_qkv_k(
    const u16* __restrict__ A, const u16* __restrict__ Bt, u16* __restrict__ Cv,
    u16* __restrict__ Vt, int M, int N, int K)
{
    __shared__ __align__(1024) u16 smem[2 * G_STRIDE];   // 112 KiB
    const int tid  = threadIdx.x;
    const int wave = tid >> 6, lane = tid & 63;
    const int quad = lane >> 4, l16 = lane & 15;
    const int wr = wave >> 2, wc = wave & 3;
    const int m0 = blockIdx.y * 256, n0 = blockIdx.x * 192;

    const int rl = lane >> 3;               // 0..7
    const int jc = (lane & 7) ^ rl;         // pre-swizzled source k-chunk
    const u16* ga = A  + (size_t)(m0 + wave * 8 + rl) * K + jc * 8;
    const u16* gb = Bt + (size_t)(n0 + wave * 8 + rl) * K + jc * 8;
    const int ldst = (wave * 64) * 8;

    f32x4 zero = {0.f, 0.f, 0.f, 0.f};
    f32x4 acc[8][3];
    #pragma unroll
    for (int i = 0; i < 8; i++)
        #pragma unroll
        for (int j = 0; j < 3; j++) acc[i][j] = zero;

    const int NT = K >> 6;

    {
        #pragma unroll
        for (int i = 0; i < 4; ++i) gload16(ga + (size_t)(i * 64) * K,      smem + i * 512 * 8 + ldst);
        #pragma unroll
        for (int i = 0; i < 3; ++i) gload16(gb + (size_t)(i * 64) * K,      smem + G_ASZ + i * 512 * 8 + ldst);
        #pragma unroll
        for (int i = 0; i < 4; ++i) gload16(ga + (size_t)(i * 64) * K + 64, smem + G_STRIDE + i * 512 * 8 + ldst);
        #pragma unroll
        for (int i = 0; i < 3; ++i) gload16(gb + (size_t)(i * 64) * K + 64, smem + G_STRIDE + G_ASZ + i * 512 * 8 + ldst);
    }
    asm volatile("s_waitcnt vmcnt(7)" ::: "memory");
    __builtin_amdgcn_s_barrier();
    asm volatile("" ::: "memory");

    const int arow = (wr * 128 + l16) * 64;
    const int brow = (wc * 48  + l16) * 64;
    const int rsw  = l16 & 7;

    for (int t = 0; t < NT; ++t) {
        const int boff = (t & 1) * G_STRIDE;
        const u16* as = smem + boff;
        const u16* bs = smem + boff + G_ASZ;
        #pragma unroll
        for (int ks = 0; ks < 2; ++ks) {
            const int ch = ((ks * 4 + quad) ^ rsw) * 8;
            short8 af[8], bfr[3];
            #pragma unroll
            for (int mf = 0; mf < 8; ++mf)
                af[mf] = *(const short8*)&as[arow + mf * (16 * 64) + ch];
            #pragma unroll
            for (int nf = 0; nf < 3; ++nf)
                bfr[nf] = *(const short8*)&bs[brow + nf * (16 * 64) + ch];
            #pragma unroll
            for (int mf = 0; mf < 8; ++mf)
                #pragma unroll
                for (int nf = 0; nf < 3; ++nf)
                    acc[mf][nf] = __builtin_amdgcn_mfma_f32_16x16x32_bf16(af[mf], bfr[nf], acc[mf][nf], 0, 0, 0);
        }
        if (t + 1 < NT) {
            asm volatile("s_waitcnt lgkmcnt(0)" ::: "memory");
            __builtin_amdgcn_s_barrier();
            asm volatile("" ::: "memory");
            if (t + 2 < NT) {
                const int kk = (t + 2) * 64;
                u16* asw = smem + boff;
                u16* bsw = smem + boff + G_ASZ;
                #pragma unroll
                for (int i = 0; i < 4; ++i)
                    gload16(ga + (size_t)(i * 64) * K + kk, asw + i * 512 * 8 + ldst);
                #pragma unroll
                for (int i = 0; i < 3; ++i)
                    gload16(gb + (size_t)(i * 64) * K + kk, bsw + i * 512 * 8 + ldst);
                asm volatile("s_waitcnt vmcnt(7)" ::: "memory");
            } else {
                asm volatile("s_waitcnt vmcnt(0)" ::: "memory");
            }
            __builtin_amdgcn_s_barrier();
            asm volatile("" ::: "memory");
        }
    }

    // ---- epilogue: q|k segmented direct store; v transposed via LDS (coalesced)
    #pragma unroll
    for (int mf = 0; mf < 8; ++mf)
        #pragma unroll
        for (int nf = 0; nf < 3; ++nf) {
            const int cc0 = n0 + wc * 48 + nf * 16;      // wave-uniform col-group base
            const int col = cc0 + l16;
            const int row0 = m0 + wr * 128 + mf * 16 + quad * 4;
            if (cc0 < 4096) {
                size_t base = ((size_t)(col >> 11) * M) * 2048 + (col & 2047);
                #pragma unroll
                for (int r = 0; r < 4; ++r)
                    Cv[base + (size_t)(row0 + r) * 2048] = f2bf(acc[mf][nf][r]);
            } else {
                const int cl = wc * 48 + nf * 16 + l16;       // local col (0..191)
                const int rlocal = wr * 128 + mf * 16 + quad * 4;  // local row (token)
                u16x4 pk;
                pk.x = f2bf(acc[mf][nf][0]); pk.y = f2bf(acc[mf][nf][1]);
                pk.z = f2bf(acc[mf][nf][2]); pk.w = f2bf(acc[mf][nf][3]);
                *(u16x4*)&smem[cl * 264 + rlocal] = pk;       // [col][264-pad row]
            }
        }
    if (n0 + 192 > 4096) {          // block has a v-part (block-uniform)
        __syncthreads();
        const int vc0 = (4096 - n0 > 0) ? (4096 - n0) : 0;    // local col where v starts
        const int nch = (192 - vc0) * 32;                     // 16B chunks along t
        const int bb = m0 >> 11, tbase = m0 & 2047;
        for (int cch = tid; cch < nch; cch += 512) {
            const int dl = vc0 + (cch >> 5);
            const int t8 = (cch & 31) * 8;
            const int vcol = n0 + dl - 4096;                  // h*128 + d
            short8 v8 = *(const short8*)&smem[dl * 264 + t8];
            *(short8*)&Vt[((size_t)(bb * AT_H + (vcol >> 7)) * 128 + (vcol & 127)) * (size_t)AT_T + tbase + t8] = v8;
        }
    }
}

// ---------------- GEMM: C[M][N] = A[M][K] * Bt[N][K]^T  (bf16 in, fp32 acc) ----------------
template<int FP32OUT>
__global__ __launch_bounds__(256, 2) void gemm_bt_k(
    const u16* __restrict__ A, const u16* __restrict__ Bt, void* __restrict__ Cv,
    int M, int N, int K)
{
    __shared__ u16 As[128 * 64];
    __shared__ u16 Bs[128 * 64];
    const int tid = threadIdx.x, wave = tid >> 6, lane = tid & 63;
    const int quad = lane >> 4, l16 = lane & 15;
    const int m0 = blockIdx.y * 128, n0 = blockIdx.x * 128;
    const int mw = (wave & 1) * 64, nw = (wave >> 1) * 64;

    f32x4 zero = {0.f, 0.f, 0.f, 0.f};
    f32x4 acc[4][4];
    #pragma unroll
    for (int i = 0; i < 4; i++)
        #pragma unroll
        for (int j = 0; j < 4; j++) acc[i][j] = zero;

    const int sr = tid >> 3;          // 0..31
    const int sj = tid & 7;           // k-chunk
    const u16* ga0 = A  + (size_t)(m0 + sr) * K + sj * 8;
    const u16* gb0 = Bt + (size_t)(n0 + sr) * K + sj * 8;
    int woff[4];
    #pragma unroll
    for (int it = 0; it < 4; ++it) {
        int r = it * 32 + sr;
        woff[it] = r * 64 + ((sj ^ (r & 7)) * 8);
    }

    short8 abuf[4], bbuf[4];
    #pragma unroll
    for (int it = 0; it < 4; ++it) {
        abuf[it] = *(const short8*)(ga0 + (size_t)(it * 32) * K);
        bbuf[it] = *(const short8*)(gb0 + (size_t)(it * 32) * K);
    }
    #pragma unroll
    for (int it = 0; it < 4; ++it) {
        *(short8*)&As[woff[it]] = abuf[it];
        *(short8*)&Bs[woff[it]] = bbuf[it];
    }
    __syncthreads();

    const int rsw = l16 & 7;

    for (int kk = 0; kk < K; kk += 64) {
        const bool pre = (kk + 64 < K);
        if (pre) {
            #pragma unroll
            for (int it = 0; it < 4; ++it) {
                abuf[it] = *(const short8*)(ga0 + (size_t)(it * 32) * K + (kk + 64));
                bbuf[it] = *(const short8*)(gb0 + (size_t)(it * 32) * K + (kk + 64));
            }
        }
        #pragma unroll
        for (int ks = 0; ks < 2; ks++) {
            const int ch = ((ks * 4 + quad) ^ rsw) * 8;
            short8 af[4], bfr[4];
            #pragma unroll
            for (int mf = 0; mf < 4; mf++)
                af[mf] = *(const short8*)&As[(mw + mf * 16 + l16) * 64 + ch];
            #pragma unroll
            for (int nf = 0; nf < 4; nf++)
                bfr[nf] = *(const short8*)&Bs[(nw + nf * 16 + l16) * 64 + ch];
            #pragma unroll
            for (int mf = 0; mf < 4; mf++)
                #pragma unroll
                for (int nf = 0; nf < 4; nf++)
                    acc[mf][nf] = __builtin_amdgcn_mfma_f32_16x16x32_bf16(af[mf], bfr[nf], acc[mf][nf], 0, 0, 0);
        }
        if (pre) {
            __syncthreads();
            #pragma unroll
            for (int it = 0; it < 4; ++it) {
                *(short8*)&As[woff[it]] = abuf[it];
                *(short8*)&Bs[woff[it]] = bbuf[it];
            }
            __syncthreads();
        }
    }

    #pragma unroll
    for (int mf = 0; mf < 4; mf++)
        #pragma unroll
        for (int nf = 0; nf < 4; nf++)
            #pragma unroll
            for (int r = 0; r < 4; r++) {
                int row = m0 + mw + mf * 16 + quad * 4 + r;
                int col = n0 + nw + nf * 16 + l16;
                if (FP32OUT) ((float*)Cv)[(size_t)row * N + col] = acc[mf][nf][r];
                else         ((u16*) Cv)[(size_t)row * N + col] = f2bf(acc[mf][nf][r]);
            }
}

// =================================================================================
// Flash attention v2: 32x32 MFMA, swapped QK^T (keys in registers), in-register
// softmax + permlane32_swap P-fragment build. 256 threads = 4 waves x 32 q-rows.
// Grid dim3(16,H,B) with (b&1) qb reversal (R8 best-measured). setprio on MFMA.
// =================================================================================
__device__ __forceinline__ void stage_kv32(u16* dst, const u16* kgp, const u16* vgp,
                                           int kt, int wave, int lane) {
    #pragma unroll
    for (int i = 0; i < 4; ++i) {
        const int g = i * 4 + wave;
        const int krow = g * 4 + (lane >> 4);
        const int kc = (lane & 15) ^ (krow & 7);
        gload16(kgp + (size_t)(kt * 64 + krow) * 2048 + kc * 8, dst + g * 512);
        const int vrow = g * 8 + (lane >> 3);
        const int vc = (lane & 7) ^ (vrow & 7);
        gload16(vgp + (size_t)vrow * AT_T + kt * 64 + vc * 8, dst + 8192 + g * 512);
    }
}

__global__ __launch_bounds__(256, 2) void attn32_k(
    const u16* __restrict__ q, const u16* __restrict__ k,
    const u16* __restrict__ vt, u16* __restrict__ o)
{
    __shared__ __align__(1024) u16 smem[2 * 16384];   // dbuf x (Ks 16KB + Vs 16KB)
    const int tid = threadIdx.x, wave = tid >> 6, lane = tid & 63;
    const int l32 = lane & 31, hi = lane >> 5;
    const int h = blockIdx.y, b = blockIdx.z;
    const int qb = (b & 1) ? (15 - (int)blockIdx.x) : (int)blockIdx.x;
    const int nkt = 2 * qb + 2;

    const u16* kgp = k  + ((size_t)(b * AT_T) * AT_H + h) * 128;
    const u16* vgp = vt + ((size_t)(b * AT_H + h) * 128) * (size_t)AT_T;

    // Q in regs: qf[kc] = Q[qrow][d = kc*16 + hi*8 + (0..8)]  (B-frag for 32x32x16)
    short8 qf[8];
    {
        const u16* qp = q + ((size_t)(b * AT_T + qb * 128 + wave * 32 + l32) * AT_H + h) * 128 + hi * 8;
        #pragma unroll
        for (int kc = 0; kc < 8; ++kc)
            qf[kc] = *(const short8*)(qp + kc * 16);
    }

    const f32x16 z16 = {0.f,0.f,0.f,0.f,0.f,0.f,0.f,0.f,0.f,0.f,0.f,0.f,0.f,0.f,0.f,0.f};
    f32x16 Oacc[4];
    #pragma unroll
    for (int i = 0; i < 4; ++i) Oacc[i] = z16;
    float l_i = 0.f;

    // prologue: stage tiles 0 and 1, wait tile 0 (vmcnt(8) leaves tile1's 8 in flight)
    stage_kv32(smem,          kgp, vgp, 0, wave, lane);
    stage_kv32(smem + 16384,  kgp, vgp, 1, wave, lane);
    asm volatile("s_waitcnt vmcnt(8)" ::: "memory");
    __builtin_amdgcn_s_barrier();
    asm volatile("" ::: "memory");

    for (int kt = 0; kt < nkt; ++kt) {
        u16* buf = smem + (kt & 1) * 16384;
        const u16* Ks = buf;
        const u16* Vs = buf + 8192;
        const int lkey0 = kt * 64 - qb * 128;      // block-local key base (may be <0)
        const bool act = (lkey0 <= wave * 32 + 31); // wave-uniform skip of fully-masked tiles

        if (act) {
            // ---- QK^T: acc[kch][reg] = S[key][qrow=l32]; keys = (r&3)+8*(r>>2)+4*hi+32*kch
            f32x16 acc[2];
            acc[0] = z16; acc[1] = z16;
            __builtin_amdgcn_s_setprio(1);
            #pragma unroll
            for (int kch = 0; kch < 2; ++kch) {
                #pragma unroll
                for (int kc = 0; kc < 8; ++kc) {
                    const int row = kch * 32 + l32;
                    const int cc = (kc * 2 + hi) ^ (lane & 7);
                    short8 af = *(const short8*)&Ks[row * 128 + cc * 8];
                    acc[kch] = __builtin_amdgcn_mfma_f32_32x32x16_bf16(af, qf[kc], acc[kch], 0, 0, 0);
                }
            }
            __builtin_amdgcn_s_setprio(0);
            // ---- masked exp (max-free) + row-sum
            float rs = 0.f;
            #pragma unroll
            for (int kch = 0; kch < 2; ++kch)
                #pragma unroll
                for (int r = 0; r < 16; ++r) {
                    const int keyb = lkey0 + kch * 32 + (r & 3) + 8 * (r >> 2) + 4 * hi;
                    float sv = acc[kch][r];
                    sv = (keyb > wave * 32 + l32) ? -1e30f : sv;
                    const float e = __expf(sv);
                    acc[kch][r] = e;
                    rs += e;
                }
            rs += __shfl_xor(rs, 32, 64);   // lanes l and l+32 hold the same qrow
            l_i += rs;
            // ---- PV: per 16-key window, build P A-frag via cvt_pk + 2 permlane32_swap
            __builtin_amdgcn_s_setprio(1);
            #pragma unroll
            for (int w16 = 0; w16 < 4; ++w16) {
                const int ch = w16 >> 1, rb = (w16 & 1) * 8;
                unsigned A0 = pack_bf2(acc[ch][rb + 0], acc[ch][rb + 1]);
                unsigned A1 = pack_bf2(acc[ch][rb + 2], acc[ch][rb + 3]);
                unsigned B0 = pack_bf2(acc[ch][rb + 4], acc[ch][rb + 5]);
                unsigned B1 = pack_bf2(acc[ch][rb + 6], acc[ch][rb + 7]);
                asm volatile("v_permlane32_swap_b32 %0, %1" : "+v"(A0), "+v"(B0));
                asm volatile("v_permlane32_swap_b32 %0, %1" : "+v"(A1), "+v"(B1));
                union { u32x4 w; short8 s; } pa;
                pa.w.x = A0; pa.w.y = A1; pa.w.z = B0; pa.w.w = B1;
                #pragma unroll
                for (int dblk = 0; dblk < 4; ++dblk) {
                    const int rowv = dblk * 32 + l32;
                    const int cv = (w16 * 2 + hi) ^ (lane & 7);
                    short8 vf = *(const short8*)&Vs[rowv * 64 + cv * 8];
                    Oacc[dblk] = __builtin_amdgcn_mfma_f32_32x32x16_bf16(pa.s, vf, Oacc[dblk], 0, 0, 0);
                }
            }
            __builtin_amdgcn_s_setprio(0);
        }

        // ---- barrier pair with liveness-correct staging (R3 pattern, vmcnt(8))
        asm volatile("s_waitcnt lgkmcnt(0)" ::: "memory");
        __builtin_amdgcn_s_barrier();
        asm volatile("" ::: "memory");
        if (kt + 2 < nkt) {
            stage_kv32(buf, kgp, vgp, kt + 2, wave, lane);
            asm volatile("s_waitcnt vmcnt(8)" ::: "memory");
        } else if (kt + 1 < nkt) {
            asm volatile("s_waitcnt vmcnt(0)" ::: "memory");
        }
        __builtin_amdgcn_s_barrier();
        asm volatile("" ::: "memory");
    }

    // ---- epilogue: distribute l_i (held at lane = qrow) to the C-layout rows, store
    float linv[16];
    #pragma unroll
    for (int r = 0; r < 16; ++r) {
        const int qr = (r & 3) + 8 * (r >> 2) + 4 * hi;
        linv[r] = 1.0f / __shfl(l_i, qr, 64);
    }
    u16* op = o + ((size_t)(b * AT_T + qb * 128 + wave * 32) * AT_H + h) * 128;
    #pragma unroll
    for (int dblk = 0; dblk < 4; ++dblk)
        #pragma unroll
        for (int r = 0; r < 16; ++r) {
            const int qr = (r & 3) + 8 * (r >> 2) + 4 * hi;
            op[(size_t)qr * 2048 + dblk * 32 + l32] = f2bf(Oacc[dblk][r] * linv[r]);
        }
}

// ---------------- launch ----------------
extern "C" void kernel_launch(void* const* d_in, const int* in_sizes, int n_in,
                              void* d_out, int out_size, void* d_ws, size_t ws_size,
                              hipStream_t stream) {
    const float* x    = (const float*)d_in[0];
    const float* w_aq = (const float*)d_in[1];
    const float* w_ak = (const float*)d_in[2];
    const float* w_av = (const float*)d_in[3];
    const float* w_ao = (const float*)d_in[4];
    float* outp = (float*)d_out;

    u16* ws   = (u16*)d_ws;
    u16* xb   = ws;                           // [4096][2048]      x, bf16
    u16* wqb  = xb   + (size_t)NROW * HD;     // [6144 n][2048 k]  (wq|wk|wv transposed)
    u16* waob = wqb  + (size_t)3 * HD * AT_M; // [2048 m][2048 hd] (w_ao^T)
    u16* qb   = waob + (size_t)HD * AT_M;     // [B,T,H,D] (then kb contiguous)
    u16* kb   = qb   + (size_t)NROW * HD;
    u16* vb   = kb   + (size_t)NROW * HD;     // unused (v written transposed directly)
    u16* vtb  = vb   + (size_t)NROW * HD;     // [B,H,D,T]
    u16* ob   = xb;                           // alias: xb dead after projections

    // 1) casts / transposes
    cast_bf16_k<<<(NROW * HD / 4 + 255) / 256, 256, 0, stream>>>(x, xb, NROW * HD / 4);
    dim3 tb(32, 8);
    tcast3_k<<<dim3(AT_D / 32, AT_M / 32, 48), tb, 0, stream>>>(w_aq, w_ak, w_av, wqb);
    tcast_k<<<dim3(AT_M / 32, HD / 32), tb, 0, stream>>>(w_ao, waob, HD, AT_M);

    // 2) fused QKV projection; v written directly as [B,H,D,T] via LDS transpose
    gemm256_qkv_k<<<dim3(3 * HD / 192, NROW / 256), 512, 0, stream>>>(xb, wqb, qb, vtb, NROW, 3 * HD, AT_M);

    // 3) RoPE on q,k (q scaled by 1/128), short8-vectorized
    rope_k<<<(NROW * AT_H * 8 + 255) / 256, 256, 0, stream>>>(qb, kb, NROW * AT_H * 8);

    // 4) attention v2 (swapped-QK 32x32, in-register softmax, permlane P-frags)
    attn32_k<<<dim3(16, AT_H, AT_B), 256, 0, stream>>>(qb, kb, vtb, ob);

    // 5) output projection (fp32 out)
    gemm_bt_k<1><<<dim3(AT_M / 128, NROW / 128), 256, 0, stream>>>(ob, waob, outp, NROW, AT_M, HD);
}